// Round 8
// baseline (1498.026 us; speedup 1.0000x reference)
//
#include <hip/hip_runtime.h>
#include <math.h>

#define BB 64
#define LL 160
#define DD 768
#define HH 4
#define NVV 197
#define SS 159

typedef unsigned short u16;
typedef __attribute__((ext_vector_type(8))) short bf16x8;
typedef __attribute__((ext_vector_type(4))) float f32x4;

union QU { uint4 u; bf16x8 v; };

__device__ __forceinline__ u16 f2bf(float a) {
  unsigned u = __builtin_bit_cast(unsigned, a);
  u = (u + 0x7FFFu + ((u >> 16) & 1u)) >> 16;
  return (u16)u;
}
__device__ __forceinline__ unsigned f2bf2(float a, float b) {
  return (unsigned)f2bf(a) | ((unsigned)f2bf(b) << 16);
}
__device__ __forceinline__ float bf2f(u16 h) {
  unsigned u = ((unsigned)h) << 16;
  return __builtin_bit_cast(float, u);
}
__device__ __forceinline__ float to_f(float x) { return x; }
__device__ __forceinline__ float to_f(u16 x) { return bf2f(x); }

__device__ __forceinline__ void async16(const u16* g, void* l) {
  __builtin_amdgcn_global_load_lds(
      (const __attribute__((address_space(1))) void*)g,
      (__attribute__((address_space(3))) void*)l, 16, 0, 0);
}

__device__ __forceinline__ uint4 load_bf8(const u16* __restrict__ P, long long rowbase,
                                          int valid, int kb, int K) {
  uint4 r;
  if (valid && (kb + 8 <= K) && (((rowbase + kb) & 7) == 0)) {
    r = *(const uint4*)(P + rowbase + kb);
  } else {
    u16 e[8];
    #pragma unroll
    for (int i = 0; i < 8; ++i) { int k = kb + i; e[i] = (valid && k < K) ? P[rowbase + k] : (u16)0; }
    r.x = e[0] | ((unsigned)e[1] << 16); r.y = e[2] | ((unsigned)e[3] << 16);
    r.z = e[4] | ((unsigned)e[5] << 16); r.w = e[6] | ((unsigned)e[7] << 16);
  }
  return r;
}

__device__ __forceinline__ uint4 load_row8(const float* __restrict__ P, long long rowbase,
                                           int valid_row, int kb, int K) {
  float f[8];
  if (valid_row && (kb + 8 <= K)) {
    const float4* p0 = (const float4*)(P + rowbase + kb);
    float4 x = p0[0], y = p0[1];
    f[0] = x.x; f[1] = x.y; f[2] = x.z; f[3] = x.w;
    f[4] = y.x; f[5] = y.y; f[6] = y.z; f[7] = y.w;
  } else {
    #pragma unroll
    for (int e = 0; e < 8; ++e) { int k = kb + e; f[e] = (valid_row && k < K) ? P[rowbase + k] : 0.f; }
  }
  uint4 r;
  r.x = f2bf2(f[0], f[1]); r.y = f2bf2(f[2], f[3]);
  r.z = f2bf2(f[4], f[5]); r.w = f2bf2(f[6], f[7]);
  return r;
}

// ---------------- 256x128 MFMA GEMM, double-buffered issue-early 2-phase, TRANSB ----------------
// C = alpha * A @ B^T (+bias) (+residB) (+=Cf if accum) (/rowdiv) (relu)
// 512 threads = 8 waves (2M x 4N), per-wave 128x32 output, BK=64, LDS 96KB (2 bufs).
__global__ __launch_bounds__(512) void gemm256(
    const u16* __restrict__ A, const u16* __restrict__ Bm,
    float* __restrict__ Cf, u16* __restrict__ Cb,
    int M, int N, int K, int lda, int ldb, int ldc, int nbx,
    float alpha, const float* __restrict__ bias, const u16* __restrict__ residB,
    const float* __restrict__ rowdiv, int relu, int accum) {
  __shared__ uint4 As[2][8][256];  // [buf][kslot][row] : 8 bf16 at k = k0 + kslot*8
  __shared__ uint4 Bs[2][8][128];

  // bijective XCD swizzle on flattened grid
  int nwg = gridDim.x;
  int id = blockIdx.x;
  int qq = nwg >> 3, rr = nwg & 7;
  int xcd = id & 7, idx = id >> 3;
  int swz = (xcd < rr ? xcd * (qq + 1) : rr * (qq + 1) + (xcd - rr) * qq) + idx;
  int bx = swz % nbx, by = swz / nbx;
  int row0 = by * 256, col0 = bx * 128;

  int t = threadIdx.x, l = t & 63, w = t >> 6;
  int wm = w >> 2, wn = w & 3;  // 2 x 4 wave grid
  int nt = K >> 6;              // K multiple of 64

  // clamped per-lane source rows (stale rows never stored)
  long long ar[4], br[2];
  #pragma unroll
  for (int i = 0; i < 4; ++i) {
    int r = row0 + i * 64 + l; if (r > M - 1) r = M - 1;
    ar[i] = (long long)r * lda + w * 8;
  }
  #pragma unroll
  for (int i = 0; i < 2; ++i) {
    int r = col0 + i * 64 + l; if (r > N - 1) r = N - 1;
    br[i] = (long long)r * ldb + w * 8;
  }

  f32x4 acc[8][2] = {};

  // prologue: stage tile 0 into buf 0
  {
    #pragma unroll
    for (int i = 0; i < 4; ++i) async16(A + ar[i], &As[0][w][i * 64]);
    #pragma unroll
    for (int i = 0; i < 2; ++i) async16(Bm + br[i], &Bs[0][w][i * 64]);
  }
  asm volatile("s_waitcnt vmcnt(0)" ::: "memory");
  __builtin_amdgcn_s_barrier();

  int buf = 0;
  for (int tt = 0; tt < nt; ++tt) {
    // issue next tile's loads FIRST (into the other buffer)
    if (tt + 1 < nt) {
      int ko = (tt + 1) << 6;
      #pragma unroll
      for (int i = 0; i < 4; ++i) async16(A + ar[i] + ko, &As[buf ^ 1][w][i * 64]);
      #pragma unroll
      for (int i = 0; i < 2; ++i) async16(Bm + br[i] + ko, &Bs[buf ^ 1][w][i * 64]);
    }
    // compute current buffer (loads fly during this)
    int kg4 = l >> 4, li = l & 15;
    #pragma unroll
    for (int ks = 0; ks < 2; ++ks) {
      int slot = ks * 4 + kg4;
      QU a[8], b[2];
      #pragma unroll
      for (int i = 0; i < 8; ++i) a[i].u = As[buf][slot][wm * 128 + i * 16 + li];
      #pragma unroll
      for (int j = 0; j < 2; ++j) b[j].u = Bs[buf][slot][wn * 32 + j * 16 + li];
      #pragma unroll
      for (int i = 0; i < 8; ++i)
        #pragma unroll
        for (int j = 0; j < 2; ++j)
          acc[i][j] = __builtin_amdgcn_mfma_f32_16x16x32_bf16(a[i].v, b[j].v, acc[i][j], 0, 0, 0);
    }
    // publish: my loads landed, everyone done reading current buf
    asm volatile("s_waitcnt vmcnt(0)" ::: "memory");
    __builtin_amdgcn_s_barrier();
    buf ^= 1;
  }

  #pragma unroll
  for (int i = 0; i < 8; ++i) {
    #pragma unroll
    for (int j = 0; j < 2; ++j) {
      int colj = col0 + wn * 32 + j * 16 + (l & 15);
      float bv = (bias && colj < N) ? bias[colj] : 0.f;
      #pragma unroll
      for (int r = 0; r < 4; ++r) {
        int gr = row0 + wm * 128 + i * 16 + (l >> 4) * 4 + r;
        if (gr < M && colj < N) {
          long long ci = (long long)gr * ldc + colj;
          float v = acc[i][j][r] * alpha + bv;
          if (residB) v += bf2f(residB[ci]);
          if (accum) v += Cf[ci];
          if (rowdiv) v /= rowdiv[gr];
          if (relu) v = fmaxf(v, 0.f);
          if (Cf) Cf[ci] = v;
          if (Cb) Cb[ci] = f2bf(v);
        }
      }
    }
  }
}

// ---------------- bf16 MFMA GEMM, 64x64 tile, batched ----------------
template<bool TRANSB>
__global__ __launch_bounds__(256) void gemm_bf16(
    const u16* __restrict__ A, const u16* __restrict__ Bm,
    float* __restrict__ Cf, u16* __restrict__ Cb,
    int M, int N, int K, int lda, int ldb, int ldc,
    long long sAb, long long sBb, long long sCb,
    float alpha, const float* __restrict__ bias, const u16* __restrict__ residB,
    const float* __restrict__ rowdiv, int relu, int accum) {
  int bb = blockIdx.z;
  A += bb * sAb;
  Bm += bb * sBb;
  long long coff = bb * sCb;

  __shared__ uint4 As4[4][64];
  __shared__ uint4 Bs4[4][64];

  int row0 = blockIdx.y * 64, col0 = blockIdx.x * 64;
  int t = threadIdx.x;
  int l = t & 63, w = t >> 6;
  int mq = (w >> 1) * 32, nq = (w & 1) * 32;

  int am = t >> 2, akq = t & 3;
  int bn = t & 63, bkq = t >> 6;

  f32x4 acc[2][2] = {};

  for (int k0 = 0; k0 < K; k0 += 32) {
    As4[akq][am] = load_bf8(A, (long long)(row0 + am) * lda, (row0 + am) < M, k0 + akq * 8, K);
    if (TRANSB) {
      Bs4[akq][am] = load_bf8(Bm, (long long)(col0 + am) * ldb, (col0 + am) < N, k0 + akq * 8, K);
    } else {
      int gn = col0 + bn;
      u16 e[8];
      #pragma unroll
      for (int i = 0; i < 8; ++i) {
        int k = k0 + bkq * 8 + i;
        e[i] = (gn < N && k < K) ? Bm[(long long)k * ldb + gn] : (u16)0;
      }
      uint4 r;
      r.x = e[0] | ((unsigned)e[1] << 16); r.y = e[2] | ((unsigned)e[3] << 16);
      r.z = e[4] | ((unsigned)e[5] << 16); r.w = e[6] | ((unsigned)e[7] << 16);
      Bs4[bkq][bn] = r;
    }
    __syncthreads();
    int kg = l >> 4, li = l & 15;
    QU a0, a1, b0, b1;
    a0.u = As4[kg][mq + li];
    a1.u = As4[kg][mq + 16 + li];
    b0.u = Bs4[kg][nq + li];
    b1.u = Bs4[kg][nq + 16 + li];
    acc[0][0] = __builtin_amdgcn_mfma_f32_16x16x32_bf16(a0.v, b0.v, acc[0][0], 0, 0, 0);
    acc[0][1] = __builtin_amdgcn_mfma_f32_16x16x32_bf16(a0.v, b1.v, acc[0][1], 0, 0, 0);
    acc[1][0] = __builtin_amdgcn_mfma_f32_16x16x32_bf16(a1.v, b0.v, acc[1][0], 0, 0, 0);
    acc[1][1] = __builtin_amdgcn_mfma_f32_16x16x32_bf16(a1.v, b1.v, acc[1][1], 0, 0, 0);
    __syncthreads();
  }

  #pragma unroll
  for (int i = 0; i < 2; ++i) {
    #pragma unroll
    for (int j = 0; j < 2; ++j) {
      int colj = col0 + nq + j * 16 + (l & 15);
      float bv = (bias && colj < N) ? bias[colj] : 0.f;
      #pragma unroll
      for (int r = 0; r < 4; ++r) {
        int gr = row0 + mq + i * 16 + (l >> 4) * 4 + r;
        if (gr < M && colj < N) {
          long long ci = coff + (long long)gr * ldc + colj;
          float v = acc[i][j][r] * alpha + bv;
          if (residB) v += bf2f(residB[ci]);
          if (accum) v += Cf[ci];
          if (rowdiv) v /= rowdiv[gr];
          if (relu) v = fmaxf(v, 0.f);
          if (Cf) Cf[ci] = v;
          if (Cb) Cb[ci] = f2bf(v);
        }
      }
    }
  }
}

// ---------------- sim GEMM (f32 in) fused with cosine*adj epilogue -> adj_ti bf16 ----------------
__global__ __launch_bounds__(256) void sim_kernel(
    const float* __restrict__ TII, const float* __restrict__ nrm,
    const float* __restrict__ adjf, u16* __restrict__ adjtiB) {
  int bb = blockIdx.z;
  const float* T = TII + (long long)bb * LL * DD;

  __shared__ uint4 As4[4][64];
  __shared__ uint4 Bs4[4][64];

  int row0 = blockIdx.y * 64, col0 = blockIdx.x * 64;
  int t = threadIdx.x;
  int l = t & 63, w = t >> 6;
  int mq = (w >> 1) * 32, nq = (w & 1) * 32;
  int am = t >> 2, akq = t & 3;

  f32x4 acc[2][2] = {};

  for (int k0 = 0; k0 < DD; k0 += 32) {
    As4[akq][am] = load_row8(T, (long long)(row0 + am) * DD, (row0 + am) < LL, k0 + akq * 8, DD);
    Bs4[akq][am] = load_row8(T, (long long)(col0 + am) * DD, (col0 + am) < LL, k0 + akq * 8, DD);
    __syncthreads();
    int kg = l >> 4, li = l & 15;
    QU a0, a1, b0, b1;
    a0.u = As4[kg][mq + li];
    a1.u = As4[kg][mq + 16 + li];
    b0.u = Bs4[kg][nq + li];
    b1.u = Bs4[kg][nq + 16 + li];
    acc[0][0] = __builtin_amdgcn_mfma_f32_16x16x32_bf16(a0.v, b0.v, acc[0][0], 0, 0, 0);
    acc[0][1] = __builtin_amdgcn_mfma_f32_16x16x32_bf16(a0.v, b1.v, acc[0][1], 0, 0, 0);
    acc[1][0] = __builtin_amdgcn_mfma_f32_16x16x32_bf16(a1.v, b0.v, acc[1][0], 0, 0, 0);
    acc[1][1] = __builtin_amdgcn_mfma_f32_16x16x32_bf16(a1.v, b1.v, acc[1][1], 0, 0, 0);
    __syncthreads();
  }

  #pragma unroll
  for (int i = 0; i < 2; ++i) {
    #pragma unroll
    for (int j = 0; j < 2; ++j) {
      int colj = col0 + nq + j * 16 + (l & 15);
      #pragma unroll
      for (int r = 0; r < 4; ++r) {
        int gr = row0 + mq + i * 16 + (l >> 4) * 4 + r;
        if (gr < LL && colj < LL) {
          float nl = nrm[bb * LL + gr], nm = nrm[bb * LL + colj];
          long long ai = ((long long)bb * LL + gr) * LL + colj;
          float s = acc[i][j][r] / fmaxf(nl * nm, 1e-16f);
          adjtiB[ai] = f2bf(adjf[ai] * s);
        }
      }
    }
  }
}

// ---------------- block reduce ----------------
__device__ __forceinline__ float block_sum(float v, float* sm) {
  #pragma unroll
  for (int o = 32; o > 0; o >>= 1) v += __shfl_down(v, o);
  int lane = threadIdx.x & 63, w = threadIdx.x >> 6;
  if (lane == 0) sm[w] = v;
  __syncthreads();
  if (threadIdx.x == 0) sm[0] = sm[0] + sm[1] + sm[2] + sm[3];
  __syncthreads();
  float r = sm[0];
  __syncthreads();
  return r;
}

// ---------------- LayerNorm ----------------
__global__ __launch_bounds__(256) void ln_kernel(const float* __restrict__ x, float* __restrict__ yf,
                                                 u16* __restrict__ yb,
                                                 const float* __restrict__ g, const float* __restrict__ b,
                                                 float* __restrict__ nrmout) {
  __shared__ float sm[4];
  long long row = blockIdx.x;
  const float* xr = x + row * DD;
  int t = threadIdx.x;
  float v0 = xr[t], v1 = xr[t + 256], v2 = xr[t + 512];
  float s = block_sum(v0 + v1 + v2, sm);
  float m = s * (1.f / 768.f);
  float d0 = v0 - m, d1 = v1 - m, d2 = v2 - m;
  float vv = block_sum(d0 * d0 + d1 * d1 + d2 * d2, sm);
  float rstd = rsqrtf(vv * (1.f / 768.f) + 1e-5f);
  float y0 = d0 * rstd * g[t] + b[t];
  float y1 = d1 * rstd * g[t + 256] + b[t + 256];
  float y2 = d2 * rstd * g[t + 512] + b[t + 512];
  if (yf) { float* yr = yf + row * DD; yr[t] = y0; yr[t + 256] = y1; yr[t + 512] = y2; }
  if (yb) { u16* yr = yb + row * DD; yr[t] = f2bf(y0); yr[t + 256] = f2bf(y1); yr[t + 512] = f2bf(y2); }
  if (nrmout) {
    float s2 = block_sum(y0 * y0 + y1 * y1 + y2 * y2, sm);
    if (t == 0) nrmout[row] = sqrtf(s2);
  }
}

// ---------------- softmax f32 in -> bf16 out (ld 200) ----------------
__global__ __launch_bounds__(256) void softmax_kernel(const float* __restrict__ S, u16* __restrict__ PB,
                                                      int nrows) {
  int row = blockIdx.x * 4 + (threadIdx.x >> 6);
  int lane = threadIdx.x & 63;
  if (row >= nrows) return;
  const float* ar = S + (long long)row * NVV;
  u16* pr = PB + (long long)row * 200;
  float vals[4];
  float mx = -1e30f;
  int cnt = 0;
  for (int i = lane; i < NVV; i += 64) { float v = ar[i]; vals[cnt++] = v; mx = fmaxf(mx, v); }
  #pragma unroll
  for (int o = 32; o > 0; o >>= 1) mx = fmaxf(mx, __shfl_xor(mx, o));
  float sum = 0.f;
  for (int j = 0; j < cnt; ++j) { vals[j] = __expf(vals[j] - mx); sum += vals[j]; }
  #pragma unroll
  for (int o = 32; o > 0; o >>= 1) sum += __shfl_xor(sum, o);
  float inv = 1.f / sum;
  cnt = 0;
  for (int i = lane; i < NVV; i += 64) pr[i] = f2bf(vals[cnt++] * inv);
  for (int i = NVV + lane; i < 200; i += 64) pr[i] = 0;
}

// ---------------- direct span-sum pool ----------------
template<typename T>
__global__ __launch_bounds__(256) void pool_kernel(const T* __restrict__ src, u16* __restrict__ dst,
                                                   const int* __restrict__ wl, const int* __restrict__ tran) {
  int b = blockIdx.x, i = blockIdx.y, d = threadIdx.x;
  long long ob = ((long long)b * LL + i) * DD;
  float r0 = 0.f, r1 = 0.f, r2 = 0.f;
  if (i > 0 && (i - 1) < wl[b]) {
    int w = i - 1;
    int st = tran[(b * SS + w) * 2];
    int en = tran[(b * SS + w) * 2 + 1];
    const T* sb = src + (long long)b * LL * DD;
    for (int s = st; s < en; ++s) {
      const T* rp = sb + (long long)(1 + s) * DD;
      r0 += to_f(rp[d]); r1 += to_f(rp[d + 256]); r2 += to_f(rp[d + 512]);
    }
  }
  dst[ob + d] = f2bf(r0);
  dst[ob + d + 256] = f2bf(r1);
  dst[ob + d + 512] = f2bf(r2);
}

// ---------------- den / den_ti ----------------
__global__ __launch_bounds__(256) void den_kernel(const float* __restrict__ adjf, const u16* __restrict__ atB,
                                                  float* __restrict__ den, float* __restrict__ den_ti) {
  __shared__ float sm[4];
  int bl = blockIdx.x, m = threadIdx.x;
  float a = 0.f, at = 0.f;
  if (m < LL) {
    long long idx = (long long)bl * LL + m;
    a = adjf[idx];
    at = bf2f(atB[idx]);
  }
  float sa = block_sum(a, sm);
  float sat = block_sum(at, sm);
  if (m == 0) { den[bl] = sa + 1.f; den_ti[bl] = sat + 1.f; }
}

// ---------------- masked mean ----------------
__global__ __launch_bounds__(256) void gcn_kernel(const u16* __restrict__ g, const float* __restrict__ mask,
                                                  u16* __restrict__ outB, int coloff) {
  int b = blockIdx.x;
  int d = blockIdx.y * 256 + threadIdx.x;
  float s = 0.f, wn = 0.f;
  for (int l = 0; l < LL; ++l) {
    float mk = mask[b * LL + l];
    wn += mk;
    s += mk * bf2f(g[((long long)b * LL + l) * DD + d]);
  }
  outB[(long long)b * (2 * DD) + coloff + d] = f2bf(s / wn);
}

// ---------------- final ----------------
__global__ __launch_bounds__(256) void final_kernel(const float* __restrict__ gb, const float* __restrict__ lf,
                                                    const float* __restrict__ ow, const float* __restrict__ ob,
                                                    float* __restrict__ out) {
  __shared__ float sm[4];
  int b = blockIdx.x / 3, c = blockIdx.x % 3;
  int t = threadIdx.x;
  float s = 0.f;
  for (int k = t; k < DD; k += 256) {
    s += gb[b * DD + k] * ow[k * 3 + c];
    s += lf[b * DD + k] * ow[(DD + k) * 3 + c];
  }
  float tot = block_sum(s, sm);
  if (t == 0) out[b * 3 + c] = tot + ob[c];
}

// ---------------- f32 -> bf16 elementwise ----------------
__global__ __launch_bounds__(256) void conv_kernel(const float4* __restrict__ x, uint2* __restrict__ y, int n4) {
  int i = blockIdx.x * 256 + threadIdx.x;
  if (i < n4) {
    float4 v = x[i];
    uint2 o;
    o.x = f2bf2(v.x, v.y);
    o.y = f2bf2(v.z, v.w);
    y[i] = o;
  }
}

// ---------------- transpose-convert ----------------
__global__ __launch_bounds__(256) void tconv_kernel(const float* __restrict__ src, u16* __restrict__ dst,
                                                    int R, int C, int lds, int ldd) {
  __shared__ float sm[32][33];
  int t = threadIdx.x;
  int tx = t & 31, ty8 = t >> 5;
  int r0 = blockIdx.y * 32, c0 = blockIdx.x * 32;
  for (int i = ty8; i < 32; i += 8) {
    int r = r0 + i, c = c0 + tx;
    sm[i][tx] = (r < R && c < C) ? src[(long long)r * lds + c] : 0.f;
  }
  __syncthreads();
  for (int i = ty8; i < 32; i += 8) {
    int c = c0 + i, r = r0 + tx;
    if (c < C && r < R) dst[(long long)c * ldd + r] = f2bf(sm[tx][i]);
  }
}

// ---------------- host wrappers ----------------
static void gemm(hipStream_t s, bool transb, const u16* A, const u16* B, float* Cf, u16* Cb,
                 int M, int N, int K, int lda, int ldb, int ldc, int batches,
                 long long sAb, long long sBb, long long sCb, float alpha,
                 const float* bias, const u16* residB, const float* rowdiv, int relu, int accum) {
  dim3 g((N + 63) / 64, (M + 63) / 64, batches);
  if (transb)
    gemm_bf16<true><<<g, 256, 0, s>>>(A, B, Cf, Cb, M, N, K, lda, ldb, ldc, sAb, sBb, sCb,
                                      alpha, bias, residB, rowdiv, relu, accum);
  else
    gemm_bf16<false><<<g, 256, 0, s>>>(A, B, Cf, Cb, M, N, K, lda, ldb, ldc, sAb, sBb, sCb,
                                       alpha, bias, residB, rowdiv, relu, accum);
}

static void gemm256h(hipStream_t s, const u16* A, const u16* B, float* Cf, u16* Cb,
                     int M, int N, int K, int lda, int ldb, int ldc, float alpha,
                     const float* bias, const u16* residB, const float* rowdiv,
                     int relu, int accum) {
  int nbx = (N + 127) / 128, nby = (M + 255) / 256;
  gemm256<<<nbx * nby, 512, 0, s>>>(A, B, Cf, Cb, M, N, K, lda, ldb, ldc, nbx,
                                    alpha, bias, residB, rowdiv, relu, accum);
}

extern "C" void kernel_launch(void* const* d_in, const int* in_sizes, int n_in,
                              void* d_out, int out_size, void* d_ws, size_t ws_size,
                              hipStream_t stream) {
  const float* text_hidden = (const float*)d_in[0];
  const float* vit_feature = (const float*)d_in[1];
  const float* pooler_out = (const float*)d_in[2];
  const float* target_mask = (const float*)d_in[3];
  const float* adj = (const float*)d_in[4];
  const float* ln_g = (const float*)d_in[5];
  const float* ln_b = (const float*)d_in[6];
  const float* wq = (const float*)d_in[7];
  const float* wk = (const float*)d_in[8];
  const float* wv = (const float*)d_in[9];
  const float* fc_w = (const float*)d_in[10];
  const float* mha_ln_g = (const float*)d_in[11];
  const float* mha_ln_b = (const float*)d_in[12];
  const float* w1b = (const float*)d_in[15];
  const float* b1b = (const float*)d_in[16];
  const float* w2b = (const float*)d_in[19];
  const float* b2b = (const float*)d_in[20];
  const float* loc_w = (const float*)d_in[21];
  const float* loc_b = (const float*)d_in[22];
  const float* out_w = (const float*)d_in[23];
  const float* out_b = (const float*)d_in[24];
  const int* word_length = (const int*)d_in[25];
  const int* tran = (const int*)d_in[26];
  float* out = (float*)d_out;

  const long long BLD = (long long)BB * LL * DD;
  const long long BND = (long long)BB * NVV * DD;

  const size_t NEED_BIG = 165000000;
  bool big = (ws_size >= NEED_BIG);

  char* base = (char*)d_ws;
  auto alloc = [&](size_t bytes) { char* p = base; base += (bytes + 255) & ~(size_t)255; return p; };

  float* R_ACC = (float*)alloc(BLD * 4);
  float* R_S = (float*)alloc((size_t)BB * LL * NVV * 4);
  u16* TFB = (u16*)alloc(BLD * 2);
  u16* vitB = (u16*)alloc(BND * 2);
  u16* X1 = (u16*)alloc(BLD * 2);
  u16* kvB = (u16*)alloc(big ? (size_t)BB * NVV * 1536 * 2 : (size_t)BND * 2);
  u16* PB = (u16*)alloc((size_t)BB * LL * 200 * 2);
  u16* adjB = (u16*)alloc((size_t)BB * LL * LL * 2);
  u16* adjtiB = (u16*)alloc((size_t)BB * LL * LL * 2);
  u16 *wqT = nullptr, *wkvT = nullptr, *fcT = nullptr;
  u16 *W0 = nullptr, *W1 = nullptr, *W2 = nullptr, *W3 = nullptr;
  if (big) {
    wqT = (u16*)alloc((size_t)3072 * 768 * 2);
    wkvT = (u16*)alloc((size_t)4 * 1536 * 768 * 2);
    fcT = (u16*)alloc((size_t)4 * 768 * 768 * 2);
  } else {
    W0 = (u16*)alloc((size_t)768 * 768 * 2);
    W1 = (u16*)alloc((size_t)768 * 768 * 2);
    W2 = (u16*)alloc((size_t)768 * 768 * 2);
    W3 = (u16*)alloc((size_t)768 * 768 * 2);
  }
  u16* w1bT = (u16*)alloc((size_t)768 * 768 * 2);
  u16* w2bT = (u16*)alloc((size_t)768 * 768 * 2);
  u16* locT = (u16*)alloc((size_t)768 * 1536 * 2);
  u16* linB = (u16*)alloc((size_t)BB * 1536 * 2);
  float* nrm = (float*)alloc((size_t)BB * LL * 4);
  float* den = (float*)alloc((size_t)BB * LL * 4);
  float* den_ti = (float*)alloc((size_t)BB * LL * 4);
  float* global_bert = (float*)alloc((size_t)BB * DD * 4);
  float* local_feat = (float*)alloc((size_t)BB * DD * 4);
  u16* tmpsB = vitB;
  u16* tmpsTiB = X1;
  u16* h1B = kvB;
  u16* h2B = TFB;
  u16* g1B = vitB;
  u16* g2B = X1;

  const float inv_sqrt_d = 1.0f / sqrtf((float)DD);
  const long long sA_L = (long long)LL * DD;

  // one-time conversions
  {
    int n4 = (int)(BND / 4);
    conv_kernel<<<(n4 + 255) / 256, 256, 0, stream>>>((const float4*)vit_feature, (uint2*)vitB, n4);
    int n4a = (int)((long long)BB * LL * LL / 4);
    conv_kernel<<<(n4a + 255) / 256, 256, 0, stream>>>((const float4*)adj, (uint2*)adjB, n4a);
    tconv_kernel<<<dim3(24, 24), 256, 0, stream>>>(w1b, w1bT, 768, 768, 768, 768);
    tconv_kernel<<<dim3(24, 24), 256, 0, stream>>>(w2b, w2bT, 768, 768, 768, 768);
    tconv_kernel<<<dim3(24, 48), 256, 0, stream>>>(loc_w, locT, 1536, 768, 768, 1536);
    if (big) {
      tconv_kernel<<<dim3(96, 24), 256, 0, stream>>>(wq, wqT, 768, 3072, 3072, 768);
      for (int h = 0; h < HH; ++h) {
        tconv_kernel<<<dim3(24, 24), 256, 0, stream>>>(wk + h * 768, wkvT + (size_t)h * 1536 * 768,
                                                       768, 768, 3072, 768);
        tconv_kernel<<<dim3(24, 24), 256, 0, stream>>>(wv + h * 768, wkvT + (size_t)h * 1536 * 768 + 768 * 768,
                                                       768, 768, 3072, 768);
        tconv_kernel<<<dim3(24, 24), 256, 0, stream>>>(fc_w + (size_t)h * 768 * 768, fcT + (size_t)h * 768 * 768,
                                                       768, 768, 768, 768);
      }
    }
  }

  // 1. text_feat = LN(text_hidden) -> bf16
  ln_kernel<<<BB * LL, 256, 0, stream>>>(text_hidden, nullptr, TFB, ln_g, ln_b, nullptr);

  // 2. per-head attention, accumulating pre-LN tii (f32)
  for (int h = 0; h < HH; ++h) {
    const u16 *qW, *kW, *vW, *fW;
    if (big) {
      qW = wqT + (size_t)h * 768 * 768;
      kW = wkvT + (size_t)h * 1536 * 768;
      vW = kW + 768 * 768;
      fW = fcT + (size_t)h * 768 * 768;
    } else {
      tconv_kernel<<<dim3(24, 24), 256, 0, stream>>>(wq + h * 768, W0, 768, 768, 3072, 768);
      tconv_kernel<<<dim3(24, 24), 256, 0, stream>>>(wk + h * 768, W1, 768, 768, 3072, 768);
      tconv_kernel<<<dim3(24, 24), 256, 0, stream>>>(wv + h * 768, W2, 768, 768, 3072, 768);
      tconv_kernel<<<dim3(24, 24), 256, 0, stream>>>(fc_w + (size_t)h * 768 * 768, W3, 768, 768, 768, 768);
      qW = W0; kW = W1; vW = W2; fW = W3;
    }
    // qB = TFB @ qW^T  (256x128 2-phase: 240 blocks)
    gemm256h(stream, TFB, qW, nullptr, X1, BB * LL, DD, DD, DD, DD, DD,
             1.f, nullptr, nullptr, nullptr, 0, 0);
    int kvld = big ? 1536 : 768;
    if (big) {
      // kv merged: one N=1536 GEMM (600 blocks)
      gemm256h(stream, vitB, kW, nullptr, kvB, BB * NVV, 1536, DD, DD, DD, 1536,
               1.f, nullptr, nullptr, nullptr, 0, 0);
    } else {
      gemm256h(stream, vitB, kW, nullptr, kvB, BB * NVV, DD, DD, DD, DD, DD,
               1.f, nullptr, nullptr, nullptr, 0, 0);
    }
    // S = qB @ k^T / sqrt(D)
    gemm(stream, true, X1, kvB, R_S, nullptr, LL, NVV, DD, DD, kvld, NVV,
         BB, sA_L, (long long)NVV * kvld, (long long)LL * NVV,
         inv_sqrt_d, nullptr, nullptr, nullptr, 0, 0);
    softmax_kernel<<<(BB * LL + 3) / 4, 256, 0, stream>>>(R_S, PB, BB * LL);
    if (!big) {
      gemm256h(stream, vitB, vW, nullptr, kvB, BB * NVV, DD, DD, DD, DD, DD,
               1.f, nullptr, nullptr, nullptr, 0, 0);
    }
    const u16* vptr = big ? kvB + 768 : kvB;
    // ctxB = P @ v
    gemm(stream, false, PB, vptr, nullptr, X1, LL, DD, NVV, 200, kvld, DD,
         BB, (long long)LL * 200, (long long)NVV * kvld, sA_L,
         1.f, nullptr, nullptr, nullptr, 0, 0);
    // tii_pre += ctxB @ fW^T (+ TFB residual at h==0)
    gemm256h(stream, X1, fW, R_ACC, nullptr, BB * LL, DD, DD, DD, DD, DD,
             1.f, nullptr, (h == 0 ? TFB : nullptr), nullptr, 0, (h > 0 ? 1 : 0));
  }

  // 3. tii = LN(tii_pre) + fused row norms
  ln_kernel<<<BB * LL, 256, 0, stream>>>(R_ACC, R_ACC, nullptr, mha_ln_g, mha_ln_b, nrm);
  // 4. adj_ti = adj * cos-sim
  sim_kernel<<<dim3(3, 3, BB), 256, 0, stream>>>(R_ACC, nrm, adj, adjtiB);
  // 5. den, den_ti
  den_kernel<<<BB * LL, 256, 0, stream>>>(adj, adjtiB, den, den_ti);
  // 6. span pools
  pool_kernel<u16><<<dim3(BB, LL), 256, 0, stream>>>(TFB, tmpsB, word_length, tran);
  pool_kernel<float><<<dim3(BB, LL), 256, 0, stream>>>(R_ACC, tmpsTiB, word_length, tran);
  // 7. h1 = adj @ tmps (batched), h2 = adj_ti @ tmps_ti
  gemm(stream, false, adjB, tmpsB, nullptr, h1B, LL, DD, LL, LL, DD, DD,
       BB, (long long)LL * LL, sA_L, sA_L, 1.f, nullptr, nullptr, nullptr, 0, 0);
  gemm(stream, false, adjtiB, tmpsTiB, nullptr, h2B, LL, DD, LL, LL, DD, DD,
       BB, (long long)LL * LL, sA_L, sA_L, 1.f, nullptr, nullptr, nullptr, 0, 0);
  // 8. g1 = relu((h1 @ w1b + b1b) / den); g2 likewise
  gemm256h(stream, h1B, w1bT, nullptr, g1B, BB * LL, DD, DD, DD, DD, DD,
           1.f, b1b, nullptr, den, 1, 0);
  gemm256h(stream, h2B, w2bT, nullptr, g2B, BB * LL, DD, DD, DD, DD, DD,
           1.f, b2b, nullptr, den_ti, 1, 0);
  // 9. masked means -> local_in bf16
  gcn_kernel<<<dim3(BB, 3), 256, 0, stream>>>(g1B, target_mask, linB, 0);
  gcn_kernel<<<dim3(BB, 3), 256, 0, stream>>>(g2B, target_mask, linB, DD);
  // 10. global_bert = LN(pooler_out)
  ln_kernel<<<BB, 256, 0, stream>>>(pooler_out, global_bert, nullptr, ln_g, ln_b, nullptr);
  // 11. local_feat = local_in @ loc_w + loc_b
  gemm(stream, true, linB, locT, local_feat, nullptr, BB, DD, 2 * DD, 2 * DD, 2 * DD, DD,
       1, 0, 0, 0, 1.f, loc_b, nullptr, nullptr, 0, 0);
  // 12. out
  final_kernel<<<BB * 3, 256, 0, stream>>>(global_bert, local_feat, out_w, out_b, out);
}

// Round 9
// 1042.526 us; speedup vs baseline: 1.4369x; 1.4369x over previous
//
#include <hip/hip_runtime.h>
#include <math.h>

#define BB 64
#define LL 160
#define DD 768
#define HH 4
#define NVV 197
#define SS 159

typedef unsigned short u16;
typedef __attribute__((ext_vector_type(8))) short bf16x8;
typedef __attribute__((ext_vector_type(4))) float f32x4;

union QU { uint4 u; bf16x8 v; };

__device__ __forceinline__ u16 f2bf(float a) {
  unsigned u = __builtin_bit_cast(unsigned, a);
  u = (u + 0x7FFFu + ((u >> 16) & 1u)) >> 16;
  return (u16)u;
}
__device__ __forceinline__ unsigned f2bf2(float a, float b) {
  return (unsigned)f2bf(a) | ((unsigned)f2bf(b) << 16);
}
__device__ __forceinline__ float bf2f(u16 h) {
  unsigned u = ((unsigned)h) << 16;
  return __builtin_bit_cast(float, u);
}
__device__ __forceinline__ float to_f(float x) { return x; }
__device__ __forceinline__ float to_f(u16 x) { return bf2f(x); }

__device__ __forceinline__ void async16(const u16* g, void* l) {
  __builtin_amdgcn_global_load_lds(
      (const __attribute__((address_space(1))) void*)g,
      (__attribute__((address_space(3))) void*)l, 16, 0, 0);
}

__device__ __forceinline__ uint4 load_bf8(const u16* __restrict__ P, long long rowbase,
                                          int valid, int kb, int K) {
  uint4 r;
  if (valid && (kb + 8 <= K) && (((rowbase + kb) & 7) == 0)) {
    r = *(const uint4*)(P + rowbase + kb);
  } else {
    u16 e[8];
    #pragma unroll
    for (int i = 0; i < 8; ++i) { int k = kb + i; e[i] = (valid && k < K) ? P[rowbase + k] : (u16)0; }
    r.x = e[0] | ((unsigned)e[1] << 16); r.y = e[2] | ((unsigned)e[3] << 16);
    r.z = e[4] | ((unsigned)e[5] << 16); r.w = e[6] | ((unsigned)e[7] << 16);
  }
  return r;
}

__device__ __forceinline__ uint4 load_row8(const float* __restrict__ P, long long rowbase,
                                           int valid_row, int kb, int K) {
  float f[8];
  if (valid_row && (kb + 8 <= K)) {
    const float4* p0 = (const float4*)(P + rowbase + kb);
    float4 x = p0[0], y = p0[1];
    f[0] = x.x; f[1] = x.y; f[2] = x.z; f[3] = x.w;
    f[4] = y.x; f[5] = y.y; f[6] = y.z; f[7] = y.w;
  } else {
    #pragma unroll
    for (int e = 0; e < 8; ++e) { int k = kb + e; f[e] = (valid_row && k < K) ? P[rowbase + k] : 0.f; }
  }
  uint4 r;
  r.x = f2bf2(f[0], f[1]); r.y = f2bf2(f[2], f[3]);
  r.z = f2bf2(f[4], f[5]); r.w = f2bf2(f[6], f[7]);
  return r;
}

// ---------------- m97-structure MFMA GEMM: 128x64 tile, single buffer, 2 barriers, TRANSB ----------------
// C = alpha * A @ B^T (+bias) (+residB) (+=Cf if accum) (/rowdiv) (relu)
__global__ __launch_bounds__(256) void gemm2ph(
    const u16* __restrict__ A, const u16* __restrict__ Bm,
    float* __restrict__ Cf, u16* __restrict__ Cb,
    int M, int N, int K, int lda, int ldb, int ldc, int nbx,
    float alpha, const float* __restrict__ bias, const u16* __restrict__ residB,
    const float* __restrict__ rowdiv, int relu, int accum) {
  __shared__ uint4 As[4][128];  // [kg][row] : 8 bf16 at k = k0+kg*8
  __shared__ uint4 Bs[4][64];

  // bijective XCD swizzle on flattened grid
  int nwg = gridDim.x;
  int id = blockIdx.x;
  int qq = nwg >> 3, rr = nwg & 7;
  int xcd = id & 7, idx = id >> 3;
  int swz = (xcd < rr ? xcd * (qq + 1) : rr * (qq + 1) + (xcd - rr) * qq) + idx;
  int bx = swz % nbx, by = swz / nbx;
  int row0 = by * 128, col0 = bx * 64;

  int t = threadIdx.x, l = t & 63, w = t >> 6;
  int wr = w * 32;
  int nt = K >> 5;  // K multiple of 32

  int ra0 = row0 + l;       if (ra0 > M - 1) ra0 = M - 1;
  int ra1 = row0 + 64 + l;  if (ra1 > M - 1) ra1 = M - 1;
  int rb0 = col0 + l;       if (rb0 > N - 1) rb0 = N - 1;
  const u16* Ap0 = A + (long long)ra0 * lda + w * 8;
  const u16* Ap1 = A + (long long)ra1 * lda + w * 8;
  const u16* Bp0 = Bm + (long long)rb0 * ldb + w * 8;

  f32x4 acc[2][4] = {};

  for (int tt = 0; tt < nt; ++tt) {
    int kk = tt << 5;
    async16(Ap0 + kk, &As[w][0]);
    async16(Ap1 + kk, &As[w][64]);
    async16(Bp0 + kk, &Bs[w][0]);
    __syncthreads();
    int kg = l >> 4, li = l & 15;
    QU a[2], b[4];
    #pragma unroll
    for (int i = 0; i < 2; ++i) a[i].u = As[kg][wr + i * 16 + li];
    #pragma unroll
    for (int j = 0; j < 4; ++j) b[j].u = Bs[kg][j * 16 + li];
    #pragma unroll
    for (int i = 0; i < 2; ++i)
      #pragma unroll
      for (int j = 0; j < 4; ++j)
        acc[i][j] = __builtin_amdgcn_mfma_f32_16x16x32_bf16(a[i].v, b[j].v, acc[i][j], 0, 0, 0);
    __syncthreads();
  }

  #pragma unroll
  for (int i = 0; i < 2; ++i) {
    #pragma unroll
    for (int j = 0; j < 4; ++j) {
      int colj = col0 + j * 16 + (l & 15);
      float bv = (bias && colj < N) ? bias[colj] : 0.f;
      #pragma unroll
      for (int r = 0; r < 4; ++r) {
        int gr = row0 + wr + i * 16 + (l >> 4) * 4 + r;
        if (gr < M && colj < N) {
          long long ci = (long long)gr * ldc + colj;
          float v = acc[i][j][r] * alpha + bv;
          if (residB) v += bf2f(residB[ci]);
          if (accum) v += Cf[ci];
          if (rowdiv) v /= rowdiv[gr];
          if (relu) v = fmaxf(v, 0.f);
          if (Cf) Cf[ci] = v;
          if (Cb) Cb[ci] = f2bf(v);
        }
      }
    }
  }
}

// ---------------- bf16 MFMA GEMM, 64x64 tile, batched ----------------
template<bool TRANSB>
__global__ __launch_bounds__(256) void gemm_bf16(
    const u16* __restrict__ A, const u16* __restrict__ Bm,
    float* __restrict__ Cf, u16* __restrict__ Cb,
    int M, int N, int K, int lda, int ldb, int ldc,
    long long sAb, long long sBb, long long sCb,
    float alpha, const float* __restrict__ bias, const u16* __restrict__ residB,
    const float* __restrict__ rowdiv, int relu, int accum) {
  int bb = blockIdx.z;
  A += bb * sAb;
  Bm += bb * sBb;
  long long coff = bb * sCb;

  __shared__ uint4 As4[4][64];
  __shared__ uint4 Bs4[4][64];

  int row0 = blockIdx.y * 64, col0 = blockIdx.x * 64;
  int t = threadIdx.x;
  int l = t & 63, w = t >> 6;
  int mq = (w >> 1) * 32, nq = (w & 1) * 32;

  int am = t >> 2, akq = t & 3;
  int bn = t & 63, bkq = t >> 6;

  f32x4 acc[2][2] = {};

  for (int k0 = 0; k0 < K; k0 += 32) {
    As4[akq][am] = load_bf8(A, (long long)(row0 + am) * lda, (row0 + am) < M, k0 + akq * 8, K);
    if (TRANSB) {
      Bs4[akq][am] = load_bf8(Bm, (long long)(col0 + am) * ldb, (col0 + am) < N, k0 + akq * 8, K);
    } else {
      int gn = col0 + bn;
      u16 e[8];
      #pragma unroll
      for (int i = 0; i < 8; ++i) {
        int k = k0 + bkq * 8 + i;
        e[i] = (gn < N && k < K) ? Bm[(long long)k * ldb + gn] : (u16)0;
      }
      uint4 r;
      r.x = e[0] | ((unsigned)e[1] << 16); r.y = e[2] | ((unsigned)e[3] << 16);
      r.z = e[4] | ((unsigned)e[5] << 16); r.w = e[6] | ((unsigned)e[7] << 16);
      Bs4[bkq][bn] = r;
    }
    __syncthreads();
    int kg = l >> 4, li = l & 15;
    QU a0, a1, b0, b1;
    a0.u = As4[kg][mq + li];
    a1.u = As4[kg][mq + 16 + li];
    b0.u = Bs4[kg][nq + li];
    b1.u = Bs4[kg][nq + 16 + li];
    acc[0][0] = __builtin_amdgcn_mfma_f32_16x16x32_bf16(a0.v, b0.v, acc[0][0], 0, 0, 0);
    acc[0][1] = __builtin_amdgcn_mfma_f32_16x16x32_bf16(a0.v, b1.v, acc[0][1], 0, 0, 0);
    acc[1][0] = __builtin_amdgcn_mfma_f32_16x16x32_bf16(a1.v, b0.v, acc[1][0], 0, 0, 0);
    acc[1][1] = __builtin_amdgcn_mfma_f32_16x16x32_bf16(a1.v, b1.v, acc[1][1], 0, 0, 0);
    __syncthreads();
  }

  #pragma unroll
  for (int i = 0; i < 2; ++i) {
    #pragma unroll
    for (int j = 0; j < 2; ++j) {
      int colj = col0 + nq + j * 16 + (l & 15);
      float bv = (bias && colj < N) ? bias[colj] : 0.f;
      #pragma unroll
      for (int r = 0; r < 4; ++r) {
        int gr = row0 + mq + i * 16 + (l >> 4) * 4 + r;
        if (gr < M && colj < N) {
          long long ci = coff + (long long)gr * ldc + colj;
          float v = acc[i][j][r] * alpha + bv;
          if (residB) v += bf2f(residB[ci]);
          if (accum) v += Cf[ci];
          if (rowdiv) v /= rowdiv[gr];
          if (relu) v = fmaxf(v, 0.f);
          if (Cf) Cf[ci] = v;
          if (Cb) Cb[ci] = f2bf(v);
        }
      }
    }
  }
}

// ---------------- sim GEMM (f32 in) fused with cosine*adj epilogue -> adj_ti bf16 ----------------
__global__ __launch_bounds__(256) void sim_kernel(
    const float* __restrict__ TII, const float* __restrict__ nrm,
    const float* __restrict__ adjf, u16* __restrict__ adjtiB) {
  int bb = blockIdx.z;
  const float* T = TII + (long long)bb * LL * DD;

  __shared__ uint4 As4[4][64];
  __shared__ uint4 Bs4[4][64];

  int row0 = blockIdx.y * 64, col0 = blockIdx.x * 64;
  int t = threadIdx.x;
  int l = t & 63, w = t >> 6;
  int mq = (w >> 1) * 32, nq = (w & 1) * 32;
  int am = t >> 2, akq = t & 3;

  f32x4 acc[2][2] = {};

  for (int k0 = 0; k0 < DD; k0 += 32) {
    As4[akq][am] = load_row8(T, (long long)(row0 + am) * DD, (row0 + am) < LL, k0 + akq * 8, DD);
    Bs4[akq][am] = load_row8(T, (long long)(col0 + am) * DD, (col0 + am) < LL, k0 + akq * 8, DD);
    __syncthreads();
    int kg = l >> 4, li = l & 15;
    QU a0, a1, b0, b1;
    a0.u = As4[kg][mq + li];
    a1.u = As4[kg][mq + 16 + li];
    b0.u = Bs4[kg][nq + li];
    b1.u = Bs4[kg][nq + 16 + li];
    acc[0][0] = __builtin_amdgcn_mfma_f32_16x16x32_bf16(a0.v, b0.v, acc[0][0], 0, 0, 0);
    acc[0][1] = __builtin_amdgcn_mfma_f32_16x16x32_bf16(a0.v, b1.v, acc[0][1], 0, 0, 0);
    acc[1][0] = __builtin_amdgcn_mfma_f32_16x16x32_bf16(a1.v, b0.v, acc[1][0], 0, 0, 0);
    acc[1][1] = __builtin_amdgcn_mfma_f32_16x16x32_bf16(a1.v, b1.v, acc[1][1], 0, 0, 0);
    __syncthreads();
  }

  #pragma unroll
  for (int i = 0; i < 2; ++i) {
    #pragma unroll
    for (int j = 0; j < 2; ++j) {
      int colj = col0 + nq + j * 16 + (l & 15);
      #pragma unroll
      for (int r = 0; r < 4; ++r) {
        int gr = row0 + mq + i * 16 + (l >> 4) * 4 + r;
        if (gr < LL && colj < LL) {
          float nl = nrm[bb * LL + gr], nm = nrm[bb * LL + colj];
          long long ai = ((long long)bb * LL + gr) * LL + colj;
          float s = acc[i][j][r] / fmaxf(nl * nm, 1e-16f);
          adjtiB[ai] = f2bf(adjf[ai] * s);
        }
      }
    }
  }
}

// ---------------- block reduce ----------------
__device__ __forceinline__ float block_sum(float v, float* sm) {
  #pragma unroll
  for (int o = 32; o > 0; o >>= 1) v += __shfl_down(v, o);
  int lane = threadIdx.x & 63, w = threadIdx.x >> 6;
  if (lane == 0) sm[w] = v;
  __syncthreads();
  if (threadIdx.x == 0) sm[0] = sm[0] + sm[1] + sm[2] + sm[3];
  __syncthreads();
  float r = sm[0];
  __syncthreads();
  return r;
}

// ---------------- LayerNorm ----------------
__global__ __launch_bounds__(256) void ln_kernel(const float* __restrict__ x, float* __restrict__ yf,
                                                 u16* __restrict__ yb,
                                                 const float* __restrict__ g, const float* __restrict__ b,
                                                 float* __restrict__ nrmout) {
  __shared__ float sm[4];
  long long row = blockIdx.x;
  const float* xr = x + row * DD;
  int t = threadIdx.x;
  float v0 = xr[t], v1 = xr[t + 256], v2 = xr[t + 512];
  float s = block_sum(v0 + v1 + v2, sm);
  float m = s * (1.f / 768.f);
  float d0 = v0 - m, d1 = v1 - m, d2 = v2 - m;
  float vv = block_sum(d0 * d0 + d1 * d1 + d2 * d2, sm);
  float rstd = rsqrtf(vv * (1.f / 768.f) + 1e-5f);
  float y0 = d0 * rstd * g[t] + b[t];
  float y1 = d1 * rstd * g[t + 256] + b[t + 256];
  float y2 = d2 * rstd * g[t + 512] + b[t + 512];
  if (yf) { float* yr = yf + row * DD; yr[t] = y0; yr[t + 256] = y1; yr[t + 512] = y2; }
  if (yb) { u16* yr = yb + row * DD; yr[t] = f2bf(y0); yr[t + 256] = f2bf(y1); yr[t + 512] = f2bf(y2); }
  if (nrmout) {
    float s2 = block_sum(y0 * y0 + y1 * y1 + y2 * y2, sm);
    if (t == 0) nrmout[row] = sqrtf(s2);
  }
}

// ---------------- softmax f32 in -> bf16 out (ld 200) ----------------
__global__ __launch_bounds__(256) void softmax_kernel(const float* __restrict__ S, u16* __restrict__ PB,
                                                      int nrows) {
  int row = blockIdx.x * 4 + (threadIdx.x >> 6);
  int lane = threadIdx.x & 63;
  if (row >= nrows) return;
  const float* ar = S + (long long)row * NVV;
  u16* pr = PB + (long long)row * 200;
  float vals[4];
  float mx = -1e30f;
  int cnt = 0;
  for (int i = lane; i < NVV; i += 64) { float v = ar[i]; vals[cnt++] = v; mx = fmaxf(mx, v); }
  #pragma unroll
  for (int o = 32; o > 0; o >>= 1) mx = fmaxf(mx, __shfl_xor(mx, o));
  float sum = 0.f;
  for (int j = 0; j < cnt; ++j) { vals[j] = __expf(vals[j] - mx); sum += vals[j]; }
  #pragma unroll
  for (int o = 32; o > 0; o >>= 1) sum += __shfl_xor(sum, o);
  float inv = 1.f / sum;
  cnt = 0;
  for (int i = lane; i < NVV; i += 64) pr[i] = f2bf(vals[cnt++] * inv);
  for (int i = NVV + lane; i < 200; i += 64) pr[i] = 0;
}

// ---------------- direct span-sum pool ----------------
template<typename T>
__global__ __launch_bounds__(256) void pool_kernel(const T* __restrict__ src, u16* __restrict__ dst,
                                                   const int* __restrict__ wl, const int* __restrict__ tran) {
  int b = blockIdx.x, i = blockIdx.y, d = threadIdx.x;
  long long ob = ((long long)b * LL + i) * DD;
  float r0 = 0.f, r1 = 0.f, r2 = 0.f;
  if (i > 0 && (i - 1) < wl[b]) {
    int w = i - 1;
    int st = tran[(b * SS + w) * 2];
    int en = tran[(b * SS + w) * 2 + 1];
    const T* sb = src + (long long)b * LL * DD;
    for (int s = st; s < en; ++s) {
      const T* rp = sb + (long long)(1 + s) * DD;
      r0 += to_f(rp[d]); r1 += to_f(rp[d + 256]); r2 += to_f(rp[d + 512]);
    }
  }
  dst[ob + d] = f2bf(r0);
  dst[ob + d + 256] = f2bf(r1);
  dst[ob + d + 512] = f2bf(r2);
}

// ---------------- den / den_ti ----------------
__global__ __launch_bounds__(256) void den_kernel(const float* __restrict__ adjf, const u16* __restrict__ atB,
                                                  float* __restrict__ den, float* __restrict__ den_ti) {
  __shared__ float sm[4];
  int bl = blockIdx.x, m = threadIdx.x;
  float a = 0.f, at = 0.f;
  if (m < LL) {
    long long idx = (long long)bl * LL + m;
    a = adjf[idx];
    at = bf2f(atB[idx]);
  }
  float sa = block_sum(a, sm);
  float sat = block_sum(at, sm);
  if (m == 0) { den[bl] = sa + 1.f; den_ti[bl] = sat + 1.f; }
}

// ---------------- masked mean ----------------
__global__ __launch_bounds__(256) void gcn_kernel(const u16* __restrict__ g, const float* __restrict__ mask,
                                                  u16* __restrict__ outB, int coloff) {
  int b = blockIdx.x;
  int d = blockIdx.y * 256 + threadIdx.x;
  float s = 0.f, wn = 0.f;
  for (int l = 0; l < LL; ++l) {
    float mk = mask[b * LL + l];
    wn += mk;
    s += mk * bf2f(g[((long long)b * LL + l) * DD + d]);
  }
  outB[(long long)b * (2 * DD) + coloff + d] = f2bf(s / wn);
}

// ---------------- final ----------------
__global__ __launch_bounds__(256) void final_kernel(const float* __restrict__ gb, const float* __restrict__ lf,
                                                    const float* __restrict__ ow, const float* __restrict__ ob,
                                                    float* __restrict__ out) {
  __shared__ float sm[4];
  int b = blockIdx.x / 3, c = blockIdx.x % 3;
  int t = threadIdx.x;
  float s = 0.f;
  for (int k = t; k < DD; k += 256) {
    s += gb[b * DD + k] * ow[k * 3 + c];
    s += lf[b * DD + k] * ow[(DD + k) * 3 + c];
  }
  float tot = block_sum(s, sm);
  if (t == 0) out[b * 3 + c] = tot + ob[c];
}

// ---------------- f32 -> bf16 elementwise ----------------
__global__ __launch_bounds__(256) void conv_kernel(const float4* __restrict__ x, uint2* __restrict__ y, int n4) {
  int i = blockIdx.x * 256 + threadIdx.x;
  if (i < n4) {
    float4 v = x[i];
    uint2 o;
    o.x = f2bf2(v.x, v.y);
    o.y = f2bf2(v.z, v.w);
    y[i] = o;
  }
}

// ---------------- transpose-convert ----------------
__global__ __launch_bounds__(256) void tconv_kernel(const float* __restrict__ src, u16* __restrict__ dst,
                                                    int R, int C, int lds, int ldd) {
  __shared__ float sm[32][33];
  int t = threadIdx.x;
  int tx = t & 31, ty8 = t >> 5;
  int r0 = blockIdx.y * 32, c0 = blockIdx.x * 32;
  for (int i = ty8; i < 32; i += 8) {
    int r = r0 + i, c = c0 + tx;
    sm[i][tx] = (r < R && c < C) ? src[(long long)r * lds + c] : 0.f;
  }
  __syncthreads();
  for (int i = ty8; i < 32; i += 8) {
    int c = c0 + i, r = r0 + tx;
    if (c < C && r < R) dst[(long long)c * ldd + r] = f2bf(sm[tx][i]);
  }
}

// ---------------- host wrappers ----------------
static void gemm(hipStream_t s, bool transb, const u16* A, const u16* B, float* Cf, u16* Cb,
                 int M, int N, int K, int lda, int ldb, int ldc, int batches,
                 long long sAb, long long sBb, long long sCb, float alpha,
                 const float* bias, const u16* residB, const float* rowdiv, int relu, int accum) {
  dim3 g((N + 63) / 64, (M + 63) / 64, batches);
  if (transb)
    gemm_bf16<true><<<g, 256, 0, s>>>(A, B, Cf, Cb, M, N, K, lda, ldb, ldc, sAb, sBb, sCb,
                                      alpha, bias, residB, rowdiv, relu, accum);
  else
    gemm_bf16<false><<<g, 256, 0, s>>>(A, B, Cf, Cb, M, N, K, lda, ldb, ldc, sAb, sBb, sCb,
                                       alpha, bias, residB, rowdiv, relu, accum);
}

static void gemm2phh(hipStream_t s, const u16* A, const u16* B, float* Cf, u16* Cb,
                     int M, int N, int K, int lda, int ldb, int ldc, float alpha,
                     const float* bias, const u16* residB, const float* rowdiv,
                     int relu, int accum) {
  int nbx = (N + 63) / 64, nby = (M + 127) / 128;
  gemm2ph<<<nbx * nby, 256, 0, s>>>(A, B, Cf, Cb, M, N, K, lda, ldb, ldc, nbx,
                                    alpha, bias, residB, rowdiv, relu, accum);
}

extern "C" void kernel_launch(void* const* d_in, const int* in_sizes, int n_in,
                              void* d_out, int out_size, void* d_ws, size_t ws_size,
                              hipStream_t stream) {
  const float* text_hidden = (const float*)d_in[0];
  const float* vit_feature = (const float*)d_in[1];
  const float* pooler_out = (const float*)d_in[2];
  const float* target_mask = (const float*)d_in[3];
  const float* adj = (const float*)d_in[4];
  const float* ln_g = (const float*)d_in[5];
  const float* ln_b = (const float*)d_in[6];
  const float* wq = (const float*)d_in[7];
  const float* wk = (const float*)d_in[8];
  const float* wv = (const float*)d_in[9];
  const float* fc_w = (const float*)d_in[10];
  const float* mha_ln_g = (const float*)d_in[11];
  const float* mha_ln_b = (const float*)d_in[12];
  const float* w1b = (const float*)d_in[15];
  const float* b1b = (const float*)d_in[16];
  const float* w2b = (const float*)d_in[19];
  const float* b2b = (const float*)d_in[20];
  const float* loc_w = (const float*)d_in[21];
  const float* loc_b = (const float*)d_in[22];
  const float* out_w = (const float*)d_in[23];
  const float* out_b = (const float*)d_in[24];
  const int* word_length = (const int*)d_in[25];
  const int* tran = (const int*)d_in[26];
  float* out = (float*)d_out;

  const long long BLD = (long long)BB * LL * DD;   // 7,864,320
  const long long BND = (long long)BB * NVV * DD;  // 9,682,944
  const long long WHD = (long long)768 * 768;      // 589,824

  char* base = (char*)d_ws;
  auto alloc = [&](size_t bytes) { char* p = base; base += (bytes + 255) & ~(size_t)255; return p; };

  float* R_ACC = (float*)alloc(BLD * 4);                     // tii_pre -> tii (f32)
  float* R_S = (float*)alloc((size_t)BB * LL * NVV * 4);     // per-head scores (f32)
  u16* TFB = (u16*)alloc(BLD * 2);                           // text_feat -> h2
  u16* vitB = (u16*)alloc(BND * 2);                          // vit bf16 -> tmps -> g1
  u16* X1 = (u16*)alloc(BLD * 2);                            // T2_h/Pv_h -> tmps_ti -> g2
  u16* H1 = (u16*)alloc(BLD * 2);                            // h1
  u16* PB = (u16*)alloc((size_t)BB * LL * 200 * 2);          // per-head probs (ld 200)
  u16* adjB = (u16*)alloc((size_t)BB * LL * LL * 2);
  u16* adjtiB = (u16*)alloc((size_t)BB * LL * LL * 2);
  u16* wqB = (u16*)alloc((size_t)768 * 3072 * 2);            // wq bf16 (row-major)
  u16* wkB = (u16*)alloc((size_t)768 * 3072 * 2);
  u16* wvB = (u16*)alloc((size_t)768 * 3072 * 2);
  u16* fcT = (u16*)alloc((size_t)4 * WHD * 2);               // fc_h^T per head
  u16* Mt = (u16*)alloc((size_t)4 * WHD * 2);                // Mt_h = (Wq_h Wk_h^T)^T
  u16* Wvf = (u16*)alloc((size_t)4 * WHD * 2);               // Wvf_h[j][f] = (Wv_h fc_h)[f][j]
  u16* w1bT = (u16*)alloc(WHD * 2);
  u16* w2bT = (u16*)alloc(WHD * 2);
  u16* locT = (u16*)alloc((size_t)768 * 1536 * 2);
  u16* linB = (u16*)alloc((size_t)BB * 1536 * 2);
  float* nrm = (float*)alloc((size_t)BB * LL * 4);
  float* den = (float*)alloc((size_t)BB * LL * 4);
  float* den_ti = (float*)alloc((size_t)BB * LL * 4);
  float* global_bert = (float*)alloc((size_t)BB * DD * 4);
  float* local_feat = (float*)alloc((size_t)BB * DD * 4);
  u16* tmpsB = vitB;
  u16* tmpsTiB = X1;
  u16* h2B = TFB;
  u16* g1B = vitB;
  u16* g2B = X1;

  const float inv_sqrt_d = 1.0f / sqrtf((float)DD);
  const long long sA_L = (long long)LL * DD;

  // ---- one-time conversions + folded-weight precompute ----
  {
    int n4v = (int)(BND / 4);
    conv_kernel<<<(n4v + 255) / 256, 256, 0, stream>>>((const float4*)vit_feature, (uint2*)vitB, n4v);
    int n4a = (int)((long long)BB * LL * LL / 4);
    conv_kernel<<<(n4a + 255) / 256, 256, 0, stream>>>((const float4*)adj, (uint2*)adjB, n4a);
    int n4w = (int)(768 * 3072 / 4);
    conv_kernel<<<(n4w + 255) / 256, 256, 0, stream>>>((const float4*)wq, (uint2*)wqB, n4w);
    conv_kernel<<<(n4w + 255) / 256, 256, 0, stream>>>((const float4*)wk, (uint2*)wkB, n4w);
    conv_kernel<<<(n4w + 255) / 256, 256, 0, stream>>>((const float4*)wv, (uint2*)wvB, n4w);
    for (int h = 0; h < HH; ++h)
      tconv_kernel<<<dim3(24, 24), 256, 0, stream>>>(fc_w + (size_t)h * WHD, fcT + (size_t)h * WHD,
                                                     768, 768, 768, 768);
    tconv_kernel<<<dim3(24, 24), 256, 0, stream>>>(w1b, w1bT, 768, 768, 768, 768);
    tconv_kernel<<<dim3(24, 24), 256, 0, stream>>>(w2b, w2bT, 768, 768, 768, 768);
    tconv_kernel<<<dim3(24, 48), 256, 0, stream>>>(loc_w, locT, 1536, 768, 768, 1536);
    // Mt_h[m][n] = sum_i wk[m][h*768+i] * wq[n][h*768+i]  (batched TRANSB)
    gemm(stream, true, wkB, wqB, nullptr, Mt, 768, 768, 768, 3072, 3072, 768,
         HH, 768, 768, WHD, 1.f, nullptr, nullptr, nullptr, 0, 0);
    // Wvf_h[j][f] = sum_d fc[h*768+d][j] * wv[f][h*768+d]  (batched TRANSB)
    gemm(stream, true, fcT, wvB, nullptr, Wvf, 768, 768, 768, 768, 3072, 768,
         HH, WHD, 768, WHD, 1.f, nullptr, nullptr, nullptr, 0, 0);
  }

  // 1. text_feat = LN(text_hidden) -> bf16
  ln_kernel<<<BB * LL, 256, 0, stream>>>(text_hidden, nullptr, TFB, ln_g, ln_b, nullptr);

  // 2. per-head attention via folded weights, accumulating pre-LN tii (f32)
  for (int h = 0; h < HH; ++h) {
    // T2_h = TFB @ Mt_h^T
    gemm2phh(stream, TFB, Mt + (size_t)h * WHD, nullptr, X1, BB * LL, DD, DD, DD, DD, DD,
             1.f, nullptr, nullptr, nullptr, 0, 0);
    // S_b = T2_b @ vit_b^T / sqrt(D)   (batched over b)
    gemm(stream, true, X1, vitB, R_S, nullptr, LL, NVV, DD, DD, DD, NVV,
         BB, sA_L, (long long)NVV * DD, (long long)LL * NVV,
         inv_sqrt_d, nullptr, nullptr, nullptr, 0, 0);
    // P = softmax(S) -> bf16 ld 200
    softmax_kernel<<<(BB * LL + 3) / 4, 256, 0, stream>>>(R_S, PB, BB * LL);
    // Pv_b = P_b @ vit_b   (batched, non-trans B; K=197)
    gemm(stream, false, PB, vitB, nullptr, X1, LL, DD, NVV, 200, DD, DD,
         BB, (long long)LL * 200, (long long)NVV * DD, sA_L,
         1.f, nullptr, nullptr, nullptr, 0, 0);
    // tii_pre += Pv_h @ Wvf_h^T (+ TFB residual at h==0)
    gemm2phh(stream, X1, Wvf + (size_t)h * WHD, R_ACC, nullptr, BB * LL, DD, DD, DD, DD, DD,
             1.f, nullptr, (h == 0 ? TFB : nullptr), nullptr, 0, (h > 0 ? 1 : 0));
  }

  // 3. tii = LN(tii_pre) + fused row norms
  ln_kernel<<<BB * LL, 256, 0, stream>>>(R_ACC, R_ACC, nullptr, mha_ln_g, mha_ln_b, nrm);
  // 4. adj_ti = adj * cos-sim
  sim_kernel<<<dim3(3, 3, BB), 256, 0, stream>>>(R_ACC, nrm, adj, adjtiB);
  // 5. den, den_ti
  den_kernel<<<BB * LL, 256, 0, stream>>>(adj, adjtiB, den, den_ti);
  // 6. span pools
  pool_kernel<u16><<<dim3(BB, LL), 256, 0, stream>>>(TFB, tmpsB, word_length, tran);
  pool_kernel<float><<<dim3(BB, LL), 256, 0, stream>>>(R_ACC, tmpsTiB, word_length, tran);
  // 7. h1 = adj @ tmps (batched) -> H1; h2 = adj_ti @ tmps_ti -> TFB
  gemm(stream, false, adjB, tmpsB, nullptr, H1, LL, DD, LL, LL, DD, DD,
       BB, (long long)LL * LL, sA_L, sA_L, 1.f, nullptr, nullptr, nullptr, 0, 0);
  gemm(stream, false, adjtiB, tmpsTiB, nullptr, h2B, LL, DD, LL, LL, DD, DD,
       BB, (long long)LL * LL, sA_L, sA_L, 1.f, nullptr, nullptr, nullptr, 0, 0);
  // 8. g1 = relu((h1 @ w1b + b1b) / den) -> vitB; g2 likewise -> X1
  gemm2phh(stream, H1, w1bT, nullptr, g1B, BB * LL, DD, DD, DD, DD, DD,
           1.f, b1b, nullptr, den, 1, 0);
  gemm2phh(stream, h2B, w2bT, nullptr, g2B, BB * LL, DD, DD, DD, DD, DD,
           1.f, b2b, nullptr, den_ti, 1, 0);
  // 9. masked means -> local_in bf16
  gcn_kernel<<<dim3(BB, 3), 256, 0, stream>>>(g1B, target_mask, linB, 0);
  gcn_kernel<<<dim3(BB, 3), 256, 0, stream>>>(g2B, target_mask, linB, DD);
  // 10. global_bert = LN(pooler_out)
  ln_kernel<<<BB, 256, 0, stream>>>(pooler_out, global_bert, nullptr, ln_g, ln_b, nullptr);
  // 11. local_feat = local_in @ loc_w + loc_b
  gemm(stream, true, linB, locT, local_feat, nullptr, BB, DD, 2 * DD, 2 * DD, 2 * DD, DD,
       1, 0, 0, 0, 1.f, loc_b, nullptr, nullptr, 0, 0);
  // 12. out
  final_kernel<<<BB * 3, 256, 0, stream>>>(global_bert, local_feat, out_w, out_b, out);
}

// Round 10
// 843.053 us; speedup vs baseline: 1.7769x; 1.2366x over previous
//
#include <hip/hip_runtime.h>
#include <math.h>

#define BB 64
#define LL 160
#define DD 768
#define HH 4
#define NVV 197
#define SS 159

typedef unsigned short u16;
typedef __attribute__((ext_vector_type(8))) short bf16x8;
typedef __attribute__((ext_vector_type(4))) float f32x4;

union QU { uint4 u; bf16x8 v; };

__device__ __forceinline__ u16 f2bf(float a) {
  unsigned u = __builtin_bit_cast(unsigned, a);
  u = (u + 0x7FFFu + ((u >> 16) & 1u)) >> 16;
  return (u16)u;
}
__device__ __forceinline__ unsigned f2bf2(float a, float b) {
  return (unsigned)f2bf(a) | ((unsigned)f2bf(b) << 16);
}
__device__ __forceinline__ float bf2f(u16 h) {
  unsigned u = ((unsigned)h) << 16;
  return __builtin_bit_cast(float, u);
}
__device__ __forceinline__ float to_f(float x) { return x; }
__device__ __forceinline__ float to_f(u16 x) { return bf2f(x); }

__device__ __forceinline__ void async16(const u16* g, void* l) {
  __builtin_amdgcn_global_load_lds(
      (const __attribute__((address_space(1))) void*)g,
      (__attribute__((address_space(3))) void*)l, 16, 0, 0);
}

__device__ __forceinline__ uint4 load_bf8(const u16* __restrict__ P, long long rowbase,
                                          int valid, int kb, int K) {
  uint4 r;
  if (valid && (kb + 8 <= K) && (((rowbase + kb) & 7) == 0)) {
    r = *(const uint4*)(P + rowbase + kb);
  } else {
    u16 e[8];
    #pragma unroll
    for (int i = 0; i < 8; ++i) { int k = kb + i; e[i] = (valid && k < K) ? P[rowbase + k] : (u16)0; }
    r.x = e[0] | ((unsigned)e[1] << 16); r.y = e[2] | ((unsigned)e[3] << 16);
    r.z = e[4] | ((unsigned)e[5] << 16); r.w = e[6] | ((unsigned)e[7] << 16);
  }
  return r;
}

__device__ __forceinline__ uint4 load_row8(const float* __restrict__ P, long long rowbase,
                                           int valid_row, int kb, int K) {
  float f[8];
  if (valid_row && (kb + 8 <= K)) {
    const float4* p0 = (const float4*)(P + rowbase + kb);
    float4 x = p0[0], y = p0[1];
    f[0] = x.x; f[1] = x.y; f[2] = x.z; f[3] = x.w;
    f[4] = y.x; f[5] = y.y; f[6] = y.z; f[7] = y.w;
  } else {
    #pragma unroll
    for (int e = 0; e < 8; ++e) { int k = kb + e; f[e] = (valid_row && k < K) ? P[rowbase + k] : 0.f; }
  }
  uint4 r;
  r.x = f2bf2(f[0], f[1]); r.y = f2bf2(f[2], f[3]);
  r.z = f2bf2(f[4], f[5]); r.w = f2bf2(f[6], f[7]);
  return r;
}

__device__ __forceinline__ uint4 load_a(const u16* P, long long rb, int v, int kb, int K) {
  return load_bf8(P, rb, v, kb, K);
}
__device__ __forceinline__ uint4 load_a(const float* P, long long rb, int v, int kb, int K) {
  return load_row8(P, rb, v, kb, K);
}

// ---------------- m97-structure MFMA GEMM: 128x64 tile, single buffer, 2 barriers, TRANSB ----------------
__global__ __launch_bounds__(256) void gemm2ph(
    const u16* __restrict__ A, const u16* __restrict__ Bm,
    float* __restrict__ Cf, u16* __restrict__ Cb,
    int M, int N, int K, int lda, int ldb, int ldc, int nbx,
    float alpha, const float* __restrict__ bias, const u16* __restrict__ residB,
    const float* __restrict__ rowdiv, int relu, int accum) {
  __shared__ uint4 As[4][128];
  __shared__ uint4 Bs[4][64];

  int nwg = gridDim.x;
  int id = blockIdx.x;
  int qq = nwg >> 3, rr = nwg & 7;
  int xcd = id & 7, idx = id >> 3;
  int swz = (xcd < rr ? xcd * (qq + 1) : rr * (qq + 1) + (xcd - rr) * qq) + idx;
  int bx = swz % nbx, by = swz / nbx;
  int row0 = by * 128, col0 = bx * 64;

  int t = threadIdx.x, l = t & 63, w = t >> 6;
  int wr = w * 32;
  int nt = K >> 5;

  int ra0 = row0 + l;       if (ra0 > M - 1) ra0 = M - 1;
  int ra1 = row0 + 64 + l;  if (ra1 > M - 1) ra1 = M - 1;
  int rb0 = col0 + l;       if (rb0 > N - 1) rb0 = N - 1;
  const u16* Ap0 = A + (long long)ra0 * lda + w * 8;
  const u16* Ap1 = A + (long long)ra1 * lda + w * 8;
  const u16* Bp0 = Bm + (long long)rb0 * ldb + w * 8;

  f32x4 acc[2][4] = {};

  for (int tt = 0; tt < nt; ++tt) {
    int kk = tt << 5;
    async16(Ap0 + kk, &As[w][0]);
    async16(Ap1 + kk, &As[w][64]);
    async16(Bp0 + kk, &Bs[w][0]);
    __syncthreads();
    int kg = l >> 4, li = l & 15;
    QU a[2], b[4];
    #pragma unroll
    for (int i = 0; i < 2; ++i) a[i].u = As[kg][wr + i * 16 + li];
    #pragma unroll
    for (int j = 0; j < 4; ++j) b[j].u = Bs[kg][j * 16 + li];
    #pragma unroll
    for (int i = 0; i < 2; ++i)
      #pragma unroll
      for (int j = 0; j < 4; ++j)
        acc[i][j] = __builtin_amdgcn_mfma_f32_16x16x32_bf16(a[i].v, b[j].v, acc[i][j], 0, 0, 0);
    __syncthreads();
  }

  #pragma unroll
  for (int i = 0; i < 2; ++i) {
    #pragma unroll
    for (int j = 0; j < 4; ++j) {
      int colj = col0 + j * 16 + (l & 15);
      float bv = (bias && colj < N) ? bias[colj] : 0.f;
      #pragma unroll
      for (int r = 0; r < 4; ++r) {
        int gr = row0 + wr + i * 16 + (l >> 4) * 4 + r;
        if (gr < M && colj < N) {
          long long ci = (long long)gr * ldc + colj;
          float v = acc[i][j][r] * alpha + bv;
          if (residB) v += bf2f(residB[ci]);
          if (accum) v += Cf[ci];
          if (rowdiv) v /= rowdiv[gr];
          if (relu) v = fmaxf(v, 0.f);
          if (Cf) Cf[ci] = v;
          if (Cb) Cb[ci] = f2bf(v);
        }
      }
    }
  }
}

// ---------------- MFMA GEMM, 64x64 tile, two-level batched, A dtype templated ----------------
template<bool TRANSB, typename TA>
__global__ __launch_bounds__(256) void gemm_bf16(
    const TA* __restrict__ A, const u16* __restrict__ Bm,
    float* __restrict__ Cf, u16* __restrict__ Cb,
    int M, int N, int K, int lda, int ldb, int ldc, int Hb,
    long long sAb, long long sAh, long long sBb, long long sBh,
    long long sCb, long long sCh,
    float alpha, const float* __restrict__ bias) {
  int bb = blockIdx.z / Hb, hh = blockIdx.z % Hb;
  A += bb * sAb + hh * sAh;
  Bm += bb * sBb + hh * sBh;
  long long coff = bb * sCb + hh * sCh;

  __shared__ uint4 As4[4][64];
  __shared__ uint4 Bs4[4][64];

  int row0 = blockIdx.y * 64, col0 = blockIdx.x * 64;
  int t = threadIdx.x;
  int l = t & 63, w = t >> 6;
  int mq = (w >> 1) * 32, nq = (w & 1) * 32;

  int am = t >> 2, akq = t & 3;
  int bn = t & 63, bkq = t >> 6;

  f32x4 acc[2][2] = {};

  for (int k0 = 0; k0 < K; k0 += 32) {
    As4[akq][am] = load_a(A, (long long)(row0 + am) * lda, (row0 + am) < M, k0 + akq * 8, K);
    if (TRANSB) {
      Bs4[akq][am] = load_bf8(Bm, (long long)(col0 + am) * ldb, (col0 + am) < N, k0 + akq * 8, K);
    } else {
      int gn = col0 + bn;
      u16 e[8];
      #pragma unroll
      for (int i = 0; i < 8; ++i) {
        int k = k0 + bkq * 8 + i;
        e[i] = (gn < N && k < K) ? Bm[(long long)k * ldb + gn] : (u16)0;
      }
      uint4 r;
      r.x = e[0] | ((unsigned)e[1] << 16); r.y = e[2] | ((unsigned)e[3] << 16);
      r.z = e[4] | ((unsigned)e[5] << 16); r.w = e[6] | ((unsigned)e[7] << 16);
      Bs4[bkq][bn] = r;
    }
    __syncthreads();
    int kg = l >> 4, li = l & 15;
    QU a0, a1, b0, b1;
    a0.u = As4[kg][mq + li];
    a1.u = As4[kg][mq + 16 + li];
    b0.u = Bs4[kg][nq + li];
    b1.u = Bs4[kg][nq + 16 + li];
    acc[0][0] = __builtin_amdgcn_mfma_f32_16x16x32_bf16(a0.v, b0.v, acc[0][0], 0, 0, 0);
    acc[0][1] = __builtin_amdgcn_mfma_f32_16x16x32_bf16(a0.v, b1.v, acc[0][1], 0, 0, 0);
    acc[1][0] = __builtin_amdgcn_mfma_f32_16x16x32_bf16(a1.v, b0.v, acc[1][0], 0, 0, 0);
    acc[1][1] = __builtin_amdgcn_mfma_f32_16x16x32_bf16(a1.v, b1.v, acc[1][1], 0, 0, 0);
    __syncthreads();
  }

  #pragma unroll
  for (int i = 0; i < 2; ++i) {
    #pragma unroll
    for (int j = 0; j < 2; ++j) {
      int colj = col0 + nq + j * 16 + (l & 15);
      float bv = (bias && colj < N) ? bias[colj] : 0.f;
      #pragma unroll
      for (int r = 0; r < 4; ++r) {
        int gr = row0 + mq + i * 16 + (l >> 4) * 4 + r;
        if (gr < M && colj < N) {
          long long ci = coff + (long long)gr * ldc + colj;
          float v = acc[i][j][r] * alpha + bv;
          if (Cf) Cf[ci] = v;
          if (Cb) Cb[ci] = f2bf(v);
        }
      }
    }
  }
}

// ---------------- sim GEMM (f32 in) fused with cosine*adj epilogue -> adj_ti bf16 ----------------
__global__ __launch_bounds__(256) void sim_kernel(
    const float* __restrict__ TII, const float* __restrict__ nrm,
    const float* __restrict__ adjf, u16* __restrict__ adjtiB) {
  int bb = blockIdx.z;
  const float* T = TII + (long long)bb * LL * DD;

  __shared__ uint4 As4[4][64];
  __shared__ uint4 Bs4[4][64];

  int row0 = blockIdx.y * 64, col0 = blockIdx.x * 64;
  int t = threadIdx.x;
  int l = t & 63, w = t >> 6;
  int mq = (w >> 1) * 32, nq = (w & 1) * 32;
  int am = t >> 2, akq = t & 3;

  f32x4 acc[2][2] = {};

  for (int k0 = 0; k0 < DD; k0 += 32) {
    As4[akq][am] = load_row8(T, (long long)(row0 + am) * DD, (row0 + am) < LL, k0 + akq * 8, DD);
    Bs4[akq][am] = load_row8(T, (long long)(col0 + am) * DD, (col0 + am) < LL, k0 + akq * 8, DD);
    __syncthreads();
    int kg = l >> 4, li = l & 15;
    QU a0, a1, b0, b1;
    a0.u = As4[kg][mq + li];
    a1.u = As4[kg][mq + 16 + li];
    b0.u = Bs4[kg][nq + li];
    b1.u = Bs4[kg][nq + 16 + li];
    acc[0][0] = __builtin_amdgcn_mfma_f32_16x16x32_bf16(a0.v, b0.v, acc[0][0], 0, 0, 0);
    acc[0][1] = __builtin_amdgcn_mfma_f32_16x16x32_bf16(a0.v, b1.v, acc[0][1], 0, 0, 0);
    acc[1][0] = __builtin_amdgcn_mfma_f32_16x16x32_bf16(a1.v, b0.v, acc[1][0], 0, 0, 0);
    acc[1][1] = __builtin_amdgcn_mfma_f32_16x16x32_bf16(a1.v, b1.v, acc[1][1], 0, 0, 0);
    __syncthreads();
  }

  #pragma unroll
  for (int i = 0; i < 2; ++i) {
    #pragma unroll
    for (int j = 0; j < 2; ++j) {
      int colj = col0 + nq + j * 16 + (l & 15);
      #pragma unroll
      for (int r = 0; r < 4; ++r) {
        int gr = row0 + mq + i * 16 + (l >> 4) * 4 + r;
        if (gr < LL && colj < LL) {
          float nl = nrm[bb * LL + gr], nm = nrm[bb * LL + colj];
          long long ai = ((long long)bb * LL + gr) * LL + colj;
          float s = acc[i][j][r] / fmaxf(nl * nm, 1e-16f);
          adjtiB[ai] = f2bf(adjf[ai] * s);
        }
      }
    }
  }
}

// ---------------- block reduce ----------------
__device__ __forceinline__ float block_sum(float v, float* sm) {
  #pragma unroll
  for (int o = 32; o > 0; o >>= 1) v += __shfl_down(v, o);
  int lane = threadIdx.x & 63, w = threadIdx.x >> 6;
  if (lane == 0) sm[w] = v;
  __syncthreads();
  if (threadIdx.x == 0) sm[0] = sm[0] + sm[1] + sm[2] + sm[3];
  __syncthreads();
  float r = sm[0];
  __syncthreads();
  return r;
}

// ---------------- LayerNorm ----------------
__global__ __launch_bounds__(256) void ln_kernel(const float* __restrict__ x, float* __restrict__ yf,
                                                 u16* __restrict__ yb,
                                                 const float* __restrict__ g, const float* __restrict__ b,
                                                 float* __restrict__ nrmout) {
  __shared__ float sm[4];
  long long row = blockIdx.x;
  const float* xr = x + row * DD;
  int t = threadIdx.x;
  float v0 = xr[t], v1 = xr[t + 256], v2 = xr[t + 512];
  float s = block_sum(v0 + v1 + v2, sm);
  float m = s * (1.f / 768.f);
  float d0 = v0 - m, d1 = v1 - m, d2 = v2 - m;
  float vv = block_sum(d0 * d0 + d1 * d1 + d2 * d2, sm);
  float rstd = rsqrtf(vv * (1.f / 768.f) + 1e-5f);
  float y0 = d0 * rstd * g[t] + b[t];
  float y1 = d1 * rstd * g[t + 256] + b[t + 256];
  float y2 = d2 * rstd * g[t + 512] + b[t + 512];
  if (yf) { float* yr = yf + row * DD; yr[t] = y0; yr[t + 256] = y1; yr[t + 512] = y2; }
  if (yb) { u16* yr = yb + row * DD; yr[t] = f2bf(y0); yr[t + 256] = f2bf(y1); yr[t + 512] = f2bf(y2); }
  if (nrmout) {
    float s2 = block_sum(y0 * y0 + y1 * y1 + y2 * y2, sm);
    if (t == 0) nrmout[row] = sqrtf(s2);
  }
}

// ---------------- in-place bf16 softmax over rows of ld 200 ----------------
__global__ __launch_bounds__(256) void softmax_bf16(u16* __restrict__ SP, int nrows) {
  int row = blockIdx.x * 4 + (threadIdx.x >> 6);
  int lane = threadIdx.x & 63;
  if (row >= nrows) return;
  u16* ar = SP + (long long)row * 200;
  float vals[4];
  float mx = -1e30f;
  int cnt = 0;
  for (int i = lane; i < NVV; i += 64) { float v = bf2f(ar[i]); vals[cnt++] = v; mx = fmaxf(mx, v); }
  #pragma unroll
  for (int o = 32; o > 0; o >>= 1) mx = fmaxf(mx, __shfl_xor(mx, o));
  float sum = 0.f;
  for (int j = 0; j < cnt; ++j) { vals[j] = __expf(vals[j] - mx); sum += vals[j]; }
  #pragma unroll
  for (int o = 32; o > 0; o >>= 1) sum += __shfl_xor(sum, o);
  float inv = 1.f / sum;
  cnt = 0;
  for (int i = lane; i < NVV; i += 64) ar[i] = f2bf(vals[cnt++] * inv);
  for (int i = NVV + lane; i < 200; i += 64) ar[i] = 0;
}

// ---------------- direct span-sum pool ----------------
template<typename T>
__global__ __launch_bounds__(256) void pool_kernel(const T* __restrict__ src, u16* __restrict__ dst,
                                                   const int* __restrict__ wl, const int* __restrict__ tran) {
  int b = blockIdx.x, i = blockIdx.y, d = threadIdx.x;
  long long ob = ((long long)b * LL + i) * DD;
  float r0 = 0.f, r1 = 0.f, r2 = 0.f;
  if (i > 0 && (i - 1) < wl[b]) {
    int w = i - 1;
    int st = tran[(b * SS + w) * 2];
    int en = tran[(b * SS + w) * 2 + 1];
    const T* sb = src + (long long)b * LL * DD;
    for (int s = st; s < en; ++s) {
      const T* rp = sb + (long long)(1 + s) * DD;
      r0 += to_f(rp[d]); r1 += to_f(rp[d + 256]); r2 += to_f(rp[d + 512]);
    }
  }
  dst[ob + d] = f2bf(r0);
  dst[ob + d + 256] = f2bf(r1);
  dst[ob + d + 512] = f2bf(r2);
}

// ---------------- den / den_ti ----------------
__global__ __launch_bounds__(256) void den_kernel(const float* __restrict__ adjf, const u16* __restrict__ atB,
                                                  float* __restrict__ den, float* __restrict__ den_ti) {
  __shared__ float sm[4];
  int bl = blockIdx.x, m = threadIdx.x;
  float a = 0.f, at = 0.f;
  if (m < LL) {
    long long idx = (long long)bl * LL + m;
    a = adjf[idx];
    at = bf2f(atB[idx]);
  }
  float sa = block_sum(a, sm);
  float sat = block_sum(at, sm);
  if (m == 0) { den[bl] = sa + 1.f; den_ti[bl] = sat + 1.f; }
}

// ---------------- masked mean ----------------
__global__ __launch_bounds__(256) void gcn_kernel(const u16* __restrict__ g, const float* __restrict__ mask,
                                                  u16* __restrict__ outB, int coloff) {
  int b = blockIdx.x;
  int d = blockIdx.y * 256 + threadIdx.x;
  float s = 0.f, wn = 0.f;
  for (int l = 0; l < LL; ++l) {
    float mk = mask[b * LL + l];
    wn += mk;
    s += mk * bf2f(g[((long long)b * LL + l) * DD + d]);
  }
  outB[(long long)b * (2 * DD) + coloff + d] = f2bf(s / wn);
}

// ---------------- final ----------------
__global__ __launch_bounds__(256) void final_kernel(const float* __restrict__ gb, const float* __restrict__ lf,
                                                    const float* __restrict__ ow, const float* __restrict__ ob,
                                                    float* __restrict__ out) {
  __shared__ float sm[4];
  int b = blockIdx.x / 3, c = blockIdx.x % 3;
  int t = threadIdx.x;
  float s = 0.f;
  for (int k = t; k < DD; k += 256) {
    s += gb[b * DD + k] * ow[k * 3 + c];
    s += lf[b * DD + k] * ow[(DD + k) * 3 + c];
  }
  float tot = block_sum(s, sm);
  if (t == 0) out[b * 3 + c] = tot + ob[c];
}

// ---------------- f32 -> bf16 elementwise ----------------
__global__ __launch_bounds__(256) void conv_kernel(const float4* __restrict__ x, uint2* __restrict__ y, int n4) {
  int i = blockIdx.x * 256 + threadIdx.x;
  if (i < n4) {
    float4 v = x[i];
    uint2 o;
    o.x = f2bf2(v.x, v.y);
    o.y = f2bf2(v.z, v.w);
    y[i] = o;
  }
}

// ---------------- transpose-convert ----------------
__global__ __launch_bounds__(256) void tconv_kernel(const float* __restrict__ src, u16* __restrict__ dst,
                                                    int R, int C, int lds, int ldd) {
  __shared__ float sm[32][33];
  int t = threadIdx.x;
  int tx = t & 31, ty8 = t >> 5;
  int r0 = blockIdx.y * 32, c0 = blockIdx.x * 32;
  for (int i = ty8; i < 32; i += 8) {
    int r = r0 + i, c = c0 + tx;
    sm[i][tx] = (r < R && c < C) ? src[(long long)r * lds + c] : 0.f;
  }
  __syncthreads();
  for (int i = ty8; i < 32; i += 8) {
    int c = c0 + i, r = r0 + tx;
    if (c < C && r < R) dst[(long long)c * ldd + r] = f2bf(sm[tx][i]);
  }
}

// ---------------- host wrappers ----------------
template<typename TA>
static void gemm(hipStream_t s, bool transb, const TA* A, const u16* B, float* Cf, u16* Cb,
                 int M, int N, int K, int lda, int ldb, int ldc, int batches, int Hb,
                 long long sAb, long long sAh, long long sBb, long long sBh,
                 long long sCb, long long sCh, float alpha, const float* bias) {
  dim3 g((N + 63) / 64, (M + 63) / 64, batches);
  if (transb)
    gemm_bf16<true, TA><<<g, 256, 0, s>>>(A, B, Cf, Cb, M, N, K, lda, ldb, ldc, Hb,
                                          sAb, sAh, sBb, sBh, sCb, sCh, alpha, bias);
  else
    gemm_bf16<false, TA><<<g, 256, 0, s>>>(A, B, Cf, Cb, M, N, K, lda, ldb, ldc, Hb,
                                           sAb, sAh, sBb, sBh, sCb, sCh, alpha, bias);
}

static void gemm2phh(hipStream_t s, const u16* A, const u16* B, float* Cf, u16* Cb,
                     int M, int N, int K, int lda, int ldb, int ldc, float alpha,
                     const float* bias, const u16* residB, const float* rowdiv,
                     int relu, int accum) {
  int nbx = (N + 63) / 64, nby = (M + 127) / 128;
  gemm2ph<<<nbx * nby, 256, 0, s>>>(A, B, Cf, Cb, M, N, K, lda, ldb, ldc, nbx,
                                    alpha, bias, residB, rowdiv, relu, accum);
}

extern "C" void kernel_launch(void* const* d_in, const int* in_sizes, int n_in,
                              void* d_out, int out_size, void* d_ws, size_t ws_size,
                              hipStream_t stream) {
  const float* text_hidden = (const float*)d_in[0];
  const float* vit_feature = (const float*)d_in[1];
  const float* pooler_out = (const float*)d_in[2];
  const float* target_mask = (const float*)d_in[3];
  const float* adj = (const float*)d_in[4];
  const float* ln_g = (const float*)d_in[5];
  const float* ln_b = (const float*)d_in[6];
  const float* wq = (const float*)d_in[7];
  const float* wk = (const float*)d_in[8];
  const float* wv = (const float*)d_in[9];
  const float* fc_w = (const float*)d_in[10];
  const float* mha_ln_g = (const float*)d_in[11];
  const float* mha_ln_b = (const float*)d_in[12];
  const float* w1b = (const float*)d_in[15];
  const float* b1b = (const float*)d_in[16];
  const float* w2b = (const float*)d_in[19];
  const float* b2b = (const float*)d_in[20];
  const float* loc_w = (const float*)d_in[21];
  const float* loc_b = (const float*)d_in[22];
  const float* out_w = (const float*)d_in[23];
  const float* out_b = (const float*)d_in[24];
  const int* word_length = (const int*)d_in[25];
  const int* tran = (const int*)d_in[26];
  float* out = (float*)d_out;

  const long long BLD = (long long)BB * LL * DD;   // 7,864,320
  const long long BND = (long long)BB * NVV * DD;  // 9,682,944
  const long long WHD = (long long)768 * 768;      // 589,824
  const long long W3K = (long long)768 * 3072;     // 2,359,296

  char* base = (char*)d_ws;
  auto alloc = [&](size_t bytes) { char* p = base; base += (bytes + 255) & ~(size_t)255; return p; };

  float* R_ACC = (float*)alloc(BLD * 4);                 // tii_pre -> tii (f32)
  u16* TFB = (u16*)alloc(BLD * 2);                       // text_feat -> h2
  u16* vitB = (u16*)alloc(BND * 2);                      // vit bf16 -> tmps -> g1
  u16* BIG = (u16*)alloc((size_t)4 * BLD * 2);           // A: wq/wk/wv/fcT bf16 | B: T2all->PvAll | C: tmpsTi, g2
  u16* Mt = (u16*)alloc((size_t)4 * WHD * 2);            // MtAll (3072 x 768), head h at row h*768
  u16* Wvf = (u16*)alloc((size_t)4 * WHD * 2);           // WvfAll (768 x 3072), head h at col h*768
  u16* SH = (u16*)alloc((size_t)BB * HH * LL * 200 * 2); // B: S4/P4 bf16 (ld 200) | C: h1
  u16* adjtiB = (u16*)alloc((size_t)BB * LL * LL * 2);
  u16* w1bT = (u16*)alloc(WHD * 2);
  u16* w2bT = (u16*)alloc(WHD * 2);
  u16* locT = (u16*)alloc((size_t)768 * 1536 * 2);
  u16* linB = (u16*)alloc((size_t)BB * 1536 * 2);
  float* nrm = (float*)alloc((size_t)BB * LL * 4);
  float* den = (float*)alloc((size_t)BB * LL * 4);
  float* den_ti = (float*)alloc((size_t)BB * LL * 4);
  float* global_bert = (float*)alloc((size_t)BB * DD * 4);
  float* local_feat = (float*)alloc((size_t)BB * DD * 4);

  // region aliases
  u16* wqB = BIG;
  u16* wkB = BIG + W3K;
  u16* wvB = BIG + 2 * W3K;
  u16* fcT = BIG + 3 * W3K;   // 4 x (768x768), head h at fcT + h*WHD
  u16* T2PV = BIG;            // (B, L, H, 768) = (10240 x 3072)
  u16* S4 = SH;               // (B, H, L, 200)
  u16* tmpsTiB = BIG;
  u16* g2B = BIG + BLD;
  u16* H1 = SH;
  u16* tmpsB = vitB;
  u16* h2B = TFB;
  u16* g1B = vitB;

  const float inv_sqrt_d = 1.0f / sqrtf((float)DD);
  const long long sA_L = (long long)LL * DD;

  // ---- phase A: conversions + folded-weight precompute ----
  {
    int n4v = (int)(BND / 4);
    conv_kernel<<<(n4v + 255) / 256, 256, 0, stream>>>((const float4*)vit_feature, (uint2*)vitB, n4v);
    int n4w = (int)(W3K / 4);
    conv_kernel<<<(n4w + 255) / 256, 256, 0, stream>>>((const float4*)wq, (uint2*)wqB, n4w);
    conv_kernel<<<(n4w + 255) / 256, 256, 0, stream>>>((const float4*)wk, (uint2*)wkB, n4w);
    conv_kernel<<<(n4w + 255) / 256, 256, 0, stream>>>((const float4*)wv, (uint2*)wvB, n4w);
    for (int h = 0; h < HH; ++h)
      tconv_kernel<<<dim3(24, 24), 256, 0, stream>>>(fc_w + (size_t)h * WHD, fcT + (size_t)h * WHD,
                                                     768, 768, 768, 768);
    tconv_kernel<<<dim3(24, 24), 256, 0, stream>>>(w1b, w1bT, 768, 768, 768, 768);
    tconv_kernel<<<dim3(24, 24), 256, 0, stream>>>(w2b, w2bT, 768, 768, 768, 768);
    tconv_kernel<<<dim3(24, 48), 256, 0, stream>>>(loc_w, locT, 1536, 768, 768, 1536);
    // MtAll: head h rows at h*768.  Mt_h[m][n] = sum_i wk[m][h*768+i]*wq[n][h*768+i]
    gemm<u16>(stream, true, wkB, wqB, nullptr, Mt, 768, 768, 768, 3072, 3072, 768,
              HH, 1, 768, 0, 768, 0, WHD, 0, 1.f, nullptr);
    // WvfAll: head h cols at h*768.  Wvf_h[j][f] = sum_d fcT_h[j][d]*wv[f][h*768+d]
    gemm<u16>(stream, true, fcT, wvB, nullptr, Wvf, 768, 768, 768, 768, 3072, 3072,
              HH, 1, WHD, 0, 768, 0, 768, 0, 1.f, nullptr);
  }

  // ---- phase B: attention (head-merged) ----
  // 1. text_feat = LN(text_hidden) -> bf16
  ln_kernel<<<BB * LL, 256, 0, stream>>>(text_hidden, nullptr, TFB, ln_g, ln_b, nullptr);
  // 2. T2all = TFB @ MtAll^T   (10240 x 3072, overwrites BIG)
  gemm2phh(stream, TFB, Mt, nullptr, T2PV, BB * LL, 4 * DD, DD, DD, DD, 4 * DD,
           1.f, nullptr, nullptr, nullptr, 0, 0);
  // 3. S[b,h] = T2[b,:,h,:] @ vit_b^T / sqrt(D) -> bf16 logits (ld 200)
  gemm<u16>(stream, true, T2PV, vitB, nullptr, S4, LL, NVV, DD, 4 * DD, DD, 200,
            BB * HH, HH, (long long)LL * 4 * DD, DD, (long long)NVV * DD, 0,
            (long long)HH * LL * 200, (long long)LL * 200, inv_sqrt_d, nullptr);
  // 4. P = softmax(S) in place
  softmax_bf16<<<(BB * HH * LL + 3) / 4, 256, 0, stream>>>(S4, BB * HH * LL);
  // 5. Pv[b,:,h,:] = P[b,h] @ vit_b   (overwrites T2all slices)
  gemm<u16>(stream, false, S4, vitB, nullptr, T2PV, LL, DD, NVV, 200, DD, 4 * DD,
            BB * HH, HH, (long long)HH * LL * 200, (long long)LL * 200,
            (long long)NVV * DD, 0, (long long)LL * 4 * DD, DD, 1.f, nullptr);
  // 6. tii_pre = PvAll @ WvfAll^T + TFB   (one K=3072 GEMM, f32 out)
  gemm2phh(stream, T2PV, Wvf, R_ACC, nullptr, BB * LL, DD, 4 * DD, 4 * DD, 4 * DD, DD,
           1.f, nullptr, TFB, nullptr, 0, 0);

  // ---- phase C ----
  // 7. tii = LN(tii_pre) + fused row norms
  ln_kernel<<<BB * LL, 256, 0, stream>>>(R_ACC, R_ACC, nullptr, mha_ln_g, mha_ln_b, nrm);
  // 8. adj_ti = adj * cos-sim
  sim_kernel<<<dim3(3, 3, BB), 256, 0, stream>>>(R_ACC, nrm, adj, adjtiB);
  // 9. den, den_ti
  den_kernel<<<BB * LL, 256, 0, stream>>>(adj, adjtiB, den, den_ti);
  // 10. span pools
  pool_kernel<u16><<<dim3(BB, LL), 256, 0, stream>>>(TFB, tmpsB, word_length, tran);
  pool_kernel<float><<<dim3(BB, LL), 256, 0, stream>>>(R_ACC, tmpsTiB, word_length, tran);
  // 11. h1 = adj @ tmps (f32 A direct) -> H1; h2 = adj_ti @ tmps_ti -> TFB
  gemm<float>(stream, false, adj, tmpsB, nullptr, H1, LL, DD, LL, LL, DD, DD,
              BB, 1, (long long)LL * LL, 0, sA_L, 0, sA_L, 0, 1.f, nullptr);
  gemm<u16>(stream, false, adjtiB, tmpsTiB, nullptr, h2B, LL, DD, LL, LL, DD, DD,
            BB, 1, (long long)LL * LL, 0, sA_L, 0, sA_L, 0, 1.f, nullptr);
  // 12. g1 = relu((h1 @ w1b + b1b) / den) -> vitB; g2 -> BIG+BLD
  gemm2phh(stream, H1, w1bT, nullptr, g1B, BB * LL, DD, DD, DD, DD, DD,
           1.f, b1b, nullptr, den, 1, 0);
  gemm2phh(stream, h2B, w2bT, nullptr, g2B, BB * LL, DD, DD, DD, DD, DD,
           1.f, b2b, nullptr, den_ti, 1, 0);
  // 13. masked means -> local_in bf16
  gcn_kernel<<<dim3(BB, 3), 256, 0, stream>>>(g1B, target_mask, linB, 0);
  gcn_kernel<<<dim3(BB, 3), 256, 0, stream>>>(g2B, target_mask, linB, DD);
  // 14. global_bert = LN(pooler_out)
  ln_kernel<<<BB, 256, 0, stream>>>(pooler_out, global_bert, nullptr, ln_g, ln_b, nullptr);
  // 15. local_feat = local_in @ loc_w + loc_b
  gemm<u16>(stream, true, linB, locT, local_feat, nullptr, BB, DD, 2 * DD, 2 * DD, 2 * DD, DD,
            1, 1, 0, 0, 0, 0, 0, 0, 1.f, loc_b);
  // 16. out
  final_kernel<<<BB * 3, 256, 0, stream>>>(global_bert, local_feat, out_w, out_b, out);
}

// Round 11
// 737.011 us; speedup vs baseline: 2.0326x; 1.1439x over previous
//
#include <hip/hip_runtime.h>
#include <math.h>

#define BB 64
#define LL 160
#define DD 768
#define HH 4
#define NVV 197
#define SS 159

typedef unsigned short u16;
typedef __attribute__((ext_vector_type(8))) short bf16x8;
typedef __attribute__((ext_vector_type(4))) float f32x4;

union QU { uint4 u; bf16x8 v; };

__device__ __forceinline__ u16 f2bf(float a) {
  unsigned u = __builtin_bit_cast(unsigned, a);
  u = (u + 0x7FFFu + ((u >> 16) & 1u)) >> 16;
  return (u16)u;
}
__device__ __forceinline__ unsigned f2bf2(float a, float b) {
  return (unsigned)f2bf(a) | ((unsigned)f2bf(b) << 16);
}
__device__ __forceinline__ float bf2f(u16 h) {
  unsigned u = ((unsigned)h) << 16;
  return __builtin_bit_cast(float, u);
}
__device__ __forceinline__ float to_f(float x) { return x; }
__device__ __forceinline__ float to_f(u16 x) { return bf2f(x); }

__device__ __forceinline__ void async16(const u16* g, void* l) {
  __builtin_amdgcn_global_load_lds(
      (const __attribute__((address_space(1))) void*)g,
      (__attribute__((address_space(3))) void*)l, 16, 0, 0);
}

__device__ __forceinline__ uint4 load_bf8(const u16* __restrict__ P, long long rowbase,
                                          int valid, int kb, int K) {
  uint4 r;
  if (valid && (kb + 8 <= K) && (((rowbase + kb) & 7) == 0)) {
    r = *(const uint4*)(P + rowbase + kb);
  } else {
    u16 e[8];
    #pragma unroll
    for (int i = 0; i < 8; ++i) { int k = kb + i; e[i] = (valid && k < K) ? P[rowbase + k] : (u16)0; }
    r.x = e[0] | ((unsigned)e[1] << 16); r.y = e[2] | ((unsigned)e[3] << 16);
    r.z = e[4] | ((unsigned)e[5] << 16); r.w = e[6] | ((unsigned)e[7] << 16);
  }
  return r;
}

__device__ __forceinline__ uint4 load_row8(const float* __restrict__ P, long long rowbase,
                                           int valid_row, int kb, int K) {
  float f[8];
  if (valid_row && (kb + 8 <= K)) {
    const float4* p0 = (const float4*)(P + rowbase + kb);
    float4 x = p0[0], y = p0[1];
    f[0] = x.x; f[1] = x.y; f[2] = x.z; f[3] = x.w;
    f[4] = y.x; f[5] = y.y; f[6] = y.z; f[7] = y.w;
  } else {
    #pragma unroll
    for (int e = 0; e < 8; ++e) { int k = kb + e; f[e] = (valid_row && k < K) ? P[rowbase + k] : 0.f; }
  }
  uint4 r;
  r.x = f2bf2(f[0], f[1]); r.y = f2bf2(f[2], f[3]);
  r.z = f2bf2(f[4], f[5]); r.w = f2bf2(f[6], f[7]);
  return r;
}

__device__ __forceinline__ uint4 load_a(const u16* P, long long rb, int v, int kb, int K) {
  return load_bf8(P, rb, v, kb, K);
}
__device__ __forceinline__ uint4 load_a(const float* P, long long rb, int v, int kb, int K) {
  return load_row8(P, rb, v, kb, K);
}

// ---------------- 256-row phase GEMM: BM=256, BN=NREP*64, BK=64, dbuf issue-early ----------------
// C = A @ B^T (+bias) (+resid set0) (/rowdiv) (relu).  Exact shapes only (256|M, BN|N, 64|K).
// DUAL=1: grid halves run two independent problem sets of identical shape.
template<int NREP, int DUAL>
__global__ __launch_bounds__(512) void gemm_ph(
    const u16* __restrict__ A0, const u16* __restrict__ B0m,
    float* __restrict__ Cf0, u16* __restrict__ Cb0,
    const u16* __restrict__ A1, const u16* __restrict__ B1m,
    float* __restrict__ Cf1, u16* __restrict__ Cb1,
    int M, int N, int K, int lda, int ldb, int ldc, int nbx,
    const float* __restrict__ bias0, const float* __restrict__ bias1,
    const u16* __restrict__ resid0,
    const float* __restrict__ rowdiv0, const float* __restrict__ rowdiv1,
    int relu) {
  constexpr int BN = NREP * 64;
  constexpr int BHALF = BN / 2;
  constexpr int BL = NREP / 2;

  __shared__ uint4 Al[2][2][8][128];     // [buf][half][kslot][row]
  __shared__ uint4 Bl[2][2][8][BHALF];

  int id = blockIdx.x;
  int nset = gridDim.x >> DUAL;
  int setid = DUAL ? (id >= nset ? 1 : 0) : 0;
  if (setid) id -= nset;
  const u16* A = setid ? A1 : A0;
  const u16* Bm = setid ? B1m : B0m;
  float* Cf = setid ? Cf1 : Cf0;
  u16* Cb = setid ? Cb1 : Cb0;
  const float* bias = setid ? bias1 : bias0;
  const float* rowdiv = setid ? rowdiv1 : rowdiv0;
  const u16* residB = setid ? (const u16*)nullptr : resid0;

  // bijective XCD swizzle within set
  int qq = nset >> 3, rr = nset & 7;
  int xcd = id & 7, idx = id >> 3;
  int swz = (xcd < rr ? xcd * (qq + 1) : rr * (qq + 1) + (xcd - rr) * qq) + idx;
  int bx = swz % nbx, by = swz / nbx;
  int row0 = by * 256, col0 = bx * BN;

  int t = threadIdx.x, l = t & 63, w = t >> 6;
  int wm = w >> 2, wn = w & 3;
  int li = l & 15, kg = l >> 4;
  int nt = K >> 6;

  int aRowL = (w & 1) * 64 + l;  // lane row within a 128-row half (A; and B when BHALF=128)
  int aKs = w >> 1;              // kslot base (+ i*4)

  f32x4 acc[8][NREP] = {};

  auto STAGE = [&](int kt, int bi) {
    long long ko = (long long)kt << 6;
    const u16* Ab = A + (long long)(row0 + aRowL) * lda + ko + aKs * 8;
    #pragma unroll
    for (int ha = 0; ha < 2; ++ha)
      #pragma unroll
      for (int i = 0; i < 2; ++i)
        async16(Ab + (long long)ha * 128 * lda + i * 32, &Al[bi][ha][i * 4 + aKs][(w & 1) * 64]);
    #pragma unroll
    for (int hb = 0; hb < 2; ++hb)
      #pragma unroll
      for (int i = 0; i < BL; ++i) {
        int s0 = i * 512 + w * 64;
        int bks = s0 / BHALF;
        int br0 = s0 % BHALF;
        async16(Bm + (long long)(col0 + hb * BHALF + br0 + l) * ldb + ko + bks * 8,
                &Bl[bi][hb][bks][br0]);
      }
  };

  // prologue
  STAGE(0, 0);
  __syncthreads();

  int buf = 0;
  for (int kt = 0; kt < nt; ++kt) {
    if (kt + 1 < nt) STAGE(kt + 1, buf ^ 1);  // issue next tile's loads first
    // B fragments (all NREP cols, both k32 halves)
    QU bF[NREP][2];
    #pragma unroll
    for (int n = 0; n < NREP; ++n) {
      int colp = wn * (16 * NREP) + n * 16 + li;
      int hb = colp / BHALF, rb = colp % BHALF;
      #pragma unroll
      for (int s32 = 0; s32 < 2; ++s32)
        bF[n][s32].u = Bl[buf][hb][s32 * 4 + kg][rb];
    }
    #pragma unroll
    for (int mh = 0; mh < 2; ++mh) {
      QU aF[4][2];
      #pragma unroll
      for (int m = 0; m < 4; ++m)
        #pragma unroll
        for (int s32 = 0; s32 < 2; ++s32)
          aF[m][s32].u = Al[buf][wm][s32 * 4 + kg][(mh * 4 + m) * 16 + li];
      __builtin_amdgcn_s_setprio(1);
      #pragma unroll
      for (int m = 0; m < 4; ++m)
        #pragma unroll
        for (int n = 0; n < NREP; ++n)
          #pragma unroll
          for (int s32 = 0; s32 < 2; ++s32)
            acc[mh * 4 + m][n] = __builtin_amdgcn_mfma_f32_16x16x32_bf16(
                aF[m][s32].v, bF[n][s32].v, acc[mh * 4 + m][n], 0, 0, 0);
      __builtin_amdgcn_s_setprio(0);
    }
    __syncthreads();  // drains vmcnt (next tile landed) + all reads of buf done
    buf ^= 1;
  }

  #pragma unroll
  for (int m = 0; m < 8; ++m)
    #pragma unroll
    for (int n = 0; n < NREP; ++n) {
      int col = col0 + wn * (16 * NREP) + n * 16 + li;
      float bv = bias ? bias[col] : 0.f;
      #pragma unroll
      for (int r = 0; r < 4; ++r) {
        int row = row0 + wm * 128 + m * 16 + kg * 4 + r;
        long long ci = (long long)row * ldc + col;
        float v = acc[m][n][r] + bv;
        if (residB) v += bf2f(residB[ci]);
        if (rowdiv) v /= rowdiv[row];
        if (relu) v = fmaxf(v, 0.f);
        if (Cf) Cf[ci] = v;
        if (Cb) Cb[ci] = f2bf(v);
      }
    }
}

// ---------------- MFMA GEMM, 64x64 tile, two-level batched, A dtype templated ----------------
template<bool TRANSB, typename TA>
__global__ __launch_bounds__(256) void gemm_bf16(
    const TA* __restrict__ A, const u16* __restrict__ Bm,
    float* __restrict__ Cf, u16* __restrict__ Cb,
    int M, int N, int K, int lda, int ldb, int ldc, int Hb,
    long long sAb, long long sAh, long long sBb, long long sBh,
    long long sCb, long long sCh,
    float alpha, const float* __restrict__ bias) {
  int bb = blockIdx.z / Hb, hh = blockIdx.z % Hb;
  A += bb * sAb + hh * sAh;
  Bm += bb * sBb + hh * sBh;
  long long coff = bb * sCb + hh * sCh;

  __shared__ uint4 As4[4][64];
  __shared__ uint4 Bs4[4][64];

  int row0 = blockIdx.y * 64, col0 = blockIdx.x * 64;
  int t = threadIdx.x;
  int l = t & 63, w = t >> 6;
  int mq = (w >> 1) * 32, nq = (w & 1) * 32;

  int am = t >> 2, akq = t & 3;
  int bn = t & 63, bkq = t >> 6;

  f32x4 acc[2][2] = {};

  for (int k0 = 0; k0 < K; k0 += 32) {
    As4[akq][am] = load_a(A, (long long)(row0 + am) * lda, (row0 + am) < M, k0 + akq * 8, K);
    if (TRANSB) {
      Bs4[akq][am] = load_bf8(Bm, (long long)(col0 + am) * ldb, (col0 + am) < N, k0 + akq * 8, K);
    } else {
      int gn = col0 + bn;
      u16 e[8];
      #pragma unroll
      for (int i = 0; i < 8; ++i) {
        int k = k0 + bkq * 8 + i;
        e[i] = (gn < N && k < K) ? Bm[(long long)k * ldb + gn] : (u16)0;
      }
      uint4 r;
      r.x = e[0] | ((unsigned)e[1] << 16); r.y = e[2] | ((unsigned)e[3] << 16);
      r.z = e[4] | ((unsigned)e[5] << 16); r.w = e[6] | ((unsigned)e[7] << 16);
      Bs4[bkq][bn] = r;
    }
    __syncthreads();
    int kg = l >> 4, li = l & 15;
    QU a0, a1, b0, b1;
    a0.u = As4[kg][mq + li];
    a1.u = As4[kg][mq + 16 + li];
    b0.u = Bs4[kg][nq + li];
    b1.u = Bs4[kg][nq + 16 + li];
    acc[0][0] = __builtin_amdgcn_mfma_f32_16x16x32_bf16(a0.v, b0.v, acc[0][0], 0, 0, 0);
    acc[0][1] = __builtin_amdgcn_mfma_f32_16x16x32_bf16(a0.v, b1.v, acc[0][1], 0, 0, 0);
    acc[1][0] = __builtin_amdgcn_mfma_f32_16x16x32_bf16(a1.v, b0.v, acc[1][0], 0, 0, 0);
    acc[1][1] = __builtin_amdgcn_mfma_f32_16x16x32_bf16(a1.v, b1.v, acc[1][1], 0, 0, 0);
    __syncthreads();
  }

  #pragma unroll
  for (int i = 0; i < 2; ++i) {
    #pragma unroll
    for (int j = 0; j < 2; ++j) {
      int colj = col0 + nq + j * 16 + (l & 15);
      float bv = (bias && colj < N) ? bias[colj] : 0.f;
      #pragma unroll
      for (int r = 0; r < 4; ++r) {
        int gr = row0 + mq + i * 16 + (l >> 4) * 4 + r;
        if (gr < M && colj < N) {
          long long ci = coff + (long long)gr * ldc + colj;
          float v = acc[i][j][r] * alpha + bv;
          if (Cf) Cf[ci] = v;
          if (Cb) Cb[ci] = f2bf(v);
        }
      }
    }
  }
}

// ---------------- sim GEMM (f32 in) fused with cosine*adj epilogue -> adj_ti bf16 ----------------
__global__ __launch_bounds__(256) void sim_kernel(
    const float* __restrict__ TII, const float* __restrict__ nrm,
    const float* __restrict__ adjf, u16* __restrict__ adjtiB) {
  int bb = blockIdx.z;
  const float* T = TII + (long long)bb * LL * DD;

  __shared__ uint4 As4[4][64];
  __shared__ uint4 Bs4[4][64];

  int row0 = blockIdx.y * 64, col0 = blockIdx.x * 64;
  int t = threadIdx.x;
  int l = t & 63, w = t >> 6;
  int mq = (w >> 1) * 32, nq = (w & 1) * 32;
  int am = t >> 2, akq = t & 3;

  f32x4 acc[2][2] = {};

  for (int k0 = 0; k0 < DD; k0 += 32) {
    As4[akq][am] = load_row8(T, (long long)(row0 + am) * DD, (row0 + am) < LL, k0 + akq * 8, DD);
    Bs4[akq][am] = load_row8(T, (long long)(col0 + am) * DD, (col0 + am) < LL, k0 + akq * 8, DD);
    __syncthreads();
    int kg = l >> 4, li = l & 15;
    QU a0, a1, b0, b1;
    a0.u = As4[kg][mq + li];
    a1.u = As4[kg][mq + 16 + li];
    b0.u = Bs4[kg][nq + li];
    b1.u = Bs4[kg][nq + 16 + li];
    acc[0][0] = __builtin_amdgcn_mfma_f32_16x16x32_bf16(a0.v, b0.v, acc[0][0], 0, 0, 0);
    acc[0][1] = __builtin_amdgcn_mfma_f32_16x16x32_bf16(a0.v, b1.v, acc[0][1], 0, 0, 0);
    acc[1][0] = __builtin_amdgcn_mfma_f32_16x16x32_bf16(a1.v, b0.v, acc[1][0], 0, 0, 0);
    acc[1][1] = __builtin_amdgcn_mfma_f32_16x16x32_bf16(a1.v, b1.v, acc[1][1], 0, 0, 0);
    __syncthreads();
  }

  #pragma unroll
  for (int i = 0; i < 2; ++i) {
    #pragma unroll
    for (int j = 0; j < 2; ++j) {
      int colj = col0 + nq + j * 16 + (l & 15);
      #pragma unroll
      for (int r = 0; r < 4; ++r) {
        int gr = row0 + mq + i * 16 + (l >> 4) * 4 + r;
        if (gr < LL && colj < LL) {
          float nl = nrm[bb * LL + gr], nm = nrm[bb * LL + colj];
          long long ai = ((long long)bb * LL + gr) * LL + colj;
          float s = acc[i][j][r] / fmaxf(nl * nm, 1e-16f);
          adjtiB[ai] = f2bf(adjf[ai] * s);
        }
      }
    }
  }
}

// ---------------- block reduce ----------------
__device__ __forceinline__ float block_sum(float v, float* sm) {
  #pragma unroll
  for (int o = 32; o > 0; o >>= 1) v += __shfl_down(v, o);
  int lane = threadIdx.x & 63, w = threadIdx.x >> 6;
  if (lane == 0) sm[w] = v;
  __syncthreads();
  if (threadIdx.x == 0) sm[0] = sm[0] + sm[1] + sm[2] + sm[3];
  __syncthreads();
  float r = sm[0];
  __syncthreads();
  return r;
}

// ---------------- LayerNorm ----------------
__global__ __launch_bounds__(256) void ln_kernel(const float* __restrict__ x, float* __restrict__ yf,
                                                 u16* __restrict__ yb,
                                                 const float* __restrict__ g, const float* __restrict__ b,
                                                 float* __restrict__ nrmout) {
  __shared__ float sm[4];
  long long row = blockIdx.x;
  const float* xr = x + row * DD;
  int t = threadIdx.x;
  float v0 = xr[t], v1 = xr[t + 256], v2 = xr[t + 512];
  float s = block_sum(v0 + v1 + v2, sm);
  float m = s * (1.f / 768.f);
  float d0 = v0 - m, d1 = v1 - m, d2 = v2 - m;
  float vv = block_sum(d0 * d0 + d1 * d1 + d2 * d2, sm);
  float rstd = rsqrtf(vv * (1.f / 768.f) + 1e-5f);
  float y0 = d0 * rstd * g[t] + b[t];
  float y1 = d1 * rstd * g[t + 256] + b[t + 256];
  float y2 = d2 * rstd * g[t + 512] + b[t + 512];
  if (yf) { float* yr = yf + row * DD; yr[t] = y0; yr[t + 256] = y1; yr[t + 512] = y2; }
  if (yb) { u16* yr = yb + row * DD; yr[t] = f2bf(y0); yr[t + 256] = f2bf(y1); yr[t + 512] = f2bf(y2); }
  if (nrmout) {
    float s2 = block_sum(y0 * y0 + y1 * y1 + y2 * y2, sm);
    if (t == 0) nrmout[row] = sqrtf(s2);
  }
}

// ---------------- in-place bf16 softmax over rows of ld 200 ----------------
__global__ __launch_bounds__(256) void softmax_bf16(u16* __restrict__ SP, int nrows) {
  int row = blockIdx.x * 4 + (threadIdx.x >> 6);
  int lane = threadIdx.x & 63;
  if (row >= nrows) return;
  u16* ar = SP + (long long)row * 200;
  float vals[4];
  float mx = -1e30f;
  int cnt = 0;
  for (int i = lane; i < NVV; i += 64) { float v = bf2f(ar[i]); vals[cnt++] = v; mx = fmaxf(mx, v); }
  #pragma unroll
  for (int o = 32; o > 0; o >>= 1) mx = fmaxf(mx, __shfl_xor(mx, o));
  float sum = 0.f;
  for (int j = 0; j < cnt; ++j) { vals[j] = __expf(vals[j] - mx); sum += vals[j]; }
  #pragma unroll
  for (int o = 32; o > 0; o >>= 1) sum += __shfl_xor(sum, o);
  float inv = 1.f / sum;
  cnt = 0;
  for (int i = lane; i < NVV; i += 64) ar[i] = f2bf(vals[cnt++] * inv);
  for (int i = NVV + lane; i < 200; i += 64) ar[i] = 0;
}

// ---------------- direct span-sum pool ----------------
template<typename T>
__global__ __launch_bounds__(256) void pool_kernel(const T* __restrict__ src, u16* __restrict__ dst,
                                                   const int* __restrict__ wl, const int* __restrict__ tran) {
  int b = blockIdx.x, i = blockIdx.y, d = threadIdx.x;
  long long ob = ((long long)b * LL + i) * DD;
  float r0 = 0.f, r1 = 0.f, r2 = 0.f;
  if (i > 0 && (i - 1) < wl[b]) {
    int w = i - 1;
    int st = tran[(b * SS + w) * 2];
    int en = tran[(b * SS + w) * 2 + 1];
    const T* sb = src + (long long)b * LL * DD;
    for (int s = st; s < en; ++s) {
      const T* rp = sb + (long long)(1 + s) * DD;
      r0 += to_f(rp[d]); r1 += to_f(rp[d + 256]); r2 += to_f(rp[d + 512]);
    }
  }
  dst[ob + d] = f2bf(r0);
  dst[ob + d + 256] = f2bf(r1);
  dst[ob + d + 512] = f2bf(r2);
}

// ---------------- den / den_ti ----------------
__global__ __launch_bounds__(256) void den_kernel(const float* __restrict__ adjf, const u16* __restrict__ atB,
                                                  float* __restrict__ den, float* __restrict__ den_ti) {
  __shared__ float sm[4];
  int bl = blockIdx.x, m = threadIdx.x;
  float a = 0.f, at = 0.f;
  if (m < LL) {
    long long idx = (long long)bl * LL + m;
    a = adjf[idx];
    at = bf2f(atB[idx]);
  }
  float sa = block_sum(a, sm);
  float sat = block_sum(at, sm);
  if (m == 0) { den[bl] = sa + 1.f; den_ti[bl] = sat + 1.f; }
}

// ---------------- masked mean ----------------
__global__ __launch_bounds__(256) void gcn_kernel(const u16* __restrict__ g, const float* __restrict__ mask,
                                                  u16* __restrict__ outB, int coloff) {
  int b = blockIdx.x;
  int d = blockIdx.y * 256 + threadIdx.x;
  float s = 0.f, wn = 0.f;
  for (int l = 0; l < LL; ++l) {
    float mk = mask[b * LL + l];
    wn += mk;
    s += mk * bf2f(g[((long long)b * LL + l) * DD + d]);
  }
  outB[(long long)b * (2 * DD) + coloff + d] = f2bf(s / wn);
}

// ---------------- final ----------------
__global__ __launch_bounds__(256) void final_kernel(const float* __restrict__ gb, const float* __restrict__ lf,
                                                    const float* __restrict__ ow, const float* __restrict__ ob,
                                                    float* __restrict__ out) {
  __shared__ float sm[4];
  int b = blockIdx.x / 3, c = blockIdx.x % 3;
  int t = threadIdx.x;
  float s = 0.f;
  for (int k = t; k < DD; k += 256) {
    s += gb[b * DD + k] * ow[k * 3 + c];
    s += lf[b * DD + k] * ow[(DD + k) * 3 + c];
  }
  float tot = block_sum(s, sm);
  if (t == 0) out[b * 3 + c] = tot + ob[c];
}

// ---------------- f32 -> bf16 elementwise ----------------
__global__ __launch_bounds__(256) void conv_kernel(const float4* __restrict__ x, uint2* __restrict__ y, int n4) {
  int i = blockIdx.x * 256 + threadIdx.x;
  if (i < n4) {
    float4 v = x[i];
    uint2 o;
    o.x = f2bf2(v.x, v.y);
    o.y = f2bf2(v.z, v.w);
    y[i] = o;
  }
}

// ---------------- transpose-convert ----------------
__global__ __launch_bounds__(256) void tconv_kernel(const float* __restrict__ src, u16* __restrict__ dst,
                                                    int R, int C, int lds, int ldd) {
  __shared__ float sm[32][33];
  int t = threadIdx.x;
  int tx = t & 31, ty8 = t >> 5;
  int r0 = blockIdx.y * 32, c0 = blockIdx.x * 32;
  for (int i = ty8; i < 32; i += 8) {
    int r = r0 + i, c = c0 + tx;
    sm[i][tx] = (r < R && c < C) ? src[(long long)r * lds + c] : 0.f;
  }
  __syncthreads();
  for (int i = ty8; i < 32; i += 8) {
    int c = c0 + i, r = r0 + tx;
    if (c < C && r < R) dst[(long long)c * ldd + r] = f2bf(sm[tx][i]);
  }
}

// ---------------- host wrappers ----------------
template<typename TA>
static void gemm(hipStream_t s, bool transb, const TA* A, const u16* B, float* Cf, u16* Cb,
                 int M, int N, int K, int lda, int ldb, int ldc, int batches, int Hb,
                 long long sAb, long long sAh, long long sBb, long long sBh,
                 long long sCb, long long sCh, float alpha, const float* bias) {
  dim3 g((N + 63) / 64, (M + 63) / 64, batches);
  if (transb)
    gemm_bf16<true, TA><<<g, 256, 0, s>>>(A, B, Cf, Cb, M, N, K, lda, ldb, ldc, Hb,
                                          sAb, sAh, sBb, sBh, sCb, sCh, alpha, bias);
  else
    gemm_bf16<false, TA><<<g, 256, 0, s>>>(A, B, Cf, Cb, M, N, K, lda, ldb, ldc, Hb,
                                           sAb, sAh, sBb, sBh, sCb, sCh, alpha, bias);
}

extern "C" void kernel_launch(void* const* d_in, const int* in_sizes, int n_in,
                              void* d_out, int out_size, void* d_ws, size_t ws_size,
                              hipStream_t stream) {
  const float* text_hidden = (const float*)d_in[0];
  const float* vit_feature = (const float*)d_in[1];
  const float* pooler_out = (const float*)d_in[2];
  const float* target_mask = (const float*)d_in[3];
  const float* adj = (const float*)d_in[4];
  const float* ln_g = (const float*)d_in[5];
  const float* ln_b = (const float*)d_in[6];
  const float* wq = (const float*)d_in[7];
  const float* wk = (const float*)d_in[8];
  const float* wv = (const float*)d_in[9];
  const float* fc_w = (const float*)d_in[10];
  const float* mha_ln_g = (const float*)d_in[11];
  const float* mha_ln_b = (const float*)d_in[12];
  const float* w1b = (const float*)d_in[15];
  const float* b1b = (const float*)d_in[16];
  const float* w2b = (const float*)d_in[19];
  const float* b2b = (const float*)d_in[20];
  const float* loc_w = (const float*)d_in[21];
  const float* loc_b = (const float*)d_in[22];
  const float* out_w = (const float*)d_in[23];
  const float* out_b = (const float*)d_in[24];
  const int* word_length = (const int*)d_in[25];
  const int* tran = (const int*)d_in[26];
  float* out = (float*)d_out;

  const long long BLD = (long long)BB * LL * DD;   // 7,864,320
  const long long BND = (long long)BB * NVV * DD;  // 9,682,944
  const long long WHD = (long long)768 * 768;      // 589,824
  const long long W3K = (long long)768 * 3072;     // 2,359,296

  char* base = (char*)d_ws;
  auto alloc = [&](size_t bytes) { char* p = base; base += (bytes + 255) & ~(size_t)255; return p; };

  float* R_ACC = (float*)alloc(BLD * 4);                 // tii_pre -> tii (f32)
  u16* TFB = (u16*)alloc(BLD * 2);                       // text_feat -> h2
  u16* vitB = (u16*)alloc(BND * 2);                      // vit bf16 -> tmps -> g1
  u16* BIG = (u16*)alloc((size_t)4 * BLD * 2);           // A: wq/wk/wv/fcT bf16 | B: T2all->PvAll | C: tmpsTi, g2
  u16* Mt = (u16*)alloc((size_t)4 * WHD * 2);            // MtAll (3072 x 768), head h at row h*768
  u16* Wvf = (u16*)alloc((size_t)4 * WHD * 2);           // WvfAll (768 x 3072), head h at col h*768
  u16* SH = (u16*)alloc((size_t)BB * HH * LL * 200 * 2); // B: S4/P4 bf16 (ld 200) | C: h1
  u16* adjtiB = (u16*)alloc((size_t)BB * LL * LL * 2);
  u16* w1bT = (u16*)alloc(WHD * 2);
  u16* w2bT = (u16*)alloc(WHD * 2);
  u16* locT = (u16*)alloc((size_t)768 * 1536 * 2);
  u16* linB = (u16*)alloc((size_t)BB * 1536 * 2);
  float* nrm = (float*)alloc((size_t)BB * LL * 4);
  float* den = (float*)alloc((size_t)BB * LL * 4);
  float* den_ti = (float*)alloc((size_t)BB * LL * 4);
  float* global_bert = (float*)alloc((size_t)BB * DD * 4);
  float* local_feat = (float*)alloc((size_t)BB * DD * 4);

  // region aliases
  u16* wqB = BIG;
  u16* wkB = BIG + W3K;
  u16* wvB = BIG + 2 * W3K;
  u16* fcT = BIG + 3 * W3K;   // 4 x (768x768), head h at fcT + h*WHD
  u16* T2PV = BIG;            // (B, L, H, 768) = (10240 x 3072)
  u16* S4 = SH;               // (B, H, L, 200)
  u16* tmpsTiB = BIG;
  u16* g2B = BIG + BLD;
  u16* H1 = SH;
  u16* tmpsB = vitB;
  u16* h2B = TFB;
  u16* g1B = vitB;

  const float inv_sqrt_d = 1.0f / sqrtf((float)DD);
  const long long sA_L = (long long)LL * DD;

  // ---- phase A: conversions + folded-weight precompute ----
  {
    int n4v = (int)(BND / 4);
    conv_kernel<<<(n4v + 255) / 256, 256, 0, stream>>>((const float4*)vit_feature, (uint2*)vitB, n4v);
    int n4w = (int)(W3K / 4);
    conv_kernel<<<(n4w + 255) / 256, 256, 0, stream>>>((const float4*)wq, (uint2*)wqB, n4w);
    conv_kernel<<<(n4w + 255) / 256, 256, 0, stream>>>((const float4*)wk, (uint2*)wkB, n4w);
    conv_kernel<<<(n4w + 255) / 256, 256, 0, stream>>>((const float4*)wv, (uint2*)wvB, n4w);
    for (int h = 0; h < HH; ++h)
      tconv_kernel<<<dim3(24, 24), 256, 0, stream>>>(fc_w + (size_t)h * WHD, fcT + (size_t)h * WHD,
                                                     768, 768, 768, 768);
    tconv_kernel<<<dim3(24, 24), 256, 0, stream>>>(w1b, w1bT, 768, 768, 768, 768);
    tconv_kernel<<<dim3(24, 24), 256, 0, stream>>>(w2b, w2bT, 768, 768, 768, 768);
    tconv_kernel<<<dim3(24, 48), 256, 0, stream>>>(loc_w, locT, 1536, 768, 768, 1536);
    // MtAll: head h rows at h*768.  Mt_h[m][n] = sum_i wk[m][h*768+i]*wq[n][h*768+i]
    gemm<u16>(stream, true, wkB, wqB, nullptr, Mt, 768, 768, 768, 3072, 3072, 768,
              HH, 1, 768, 0, 768, 0, WHD, 0, 1.f, nullptr);
    // WvfAll: head h cols at h*768.  Wvf_h[j][f] = sum_d fcT_h[j][d]*wv[f][h*768+d]
    gemm<u16>(stream, true, fcT, wvB, nullptr, Wvf, 768, 768, 768, 768, 3072, 3072,
              HH, 1, WHD, 0, 768, 0, 768, 0, 1.f, nullptr);
  }

  // ---- phase B: attention (head-merged) ----
  // 1. text_feat = LN(text_hidden) -> bf16
  ln_kernel<<<BB * LL, 256, 0, stream>>>(text_hidden, nullptr, TFB, ln_g, ln_b, nullptr);
  // 2. T2all = TFB @ MtAll^T   (10240 x 3072) — 256-row phase kernel, 480 blocks
  gemm_ph<4, 0><<<480, 512, 0, stream>>>(TFB, Mt, nullptr, T2PV,
                                         nullptr, nullptr, nullptr, nullptr,
                                         BB * LL, 4 * DD, DD, DD, DD, 4 * DD, 12,
                                         nullptr, nullptr, nullptr, nullptr, nullptr, 0);
  // 3. S[b,h] = T2[b,:,h,:] @ vit_b^T / sqrt(D) -> bf16 logits (ld 200)
  gemm<u16>(stream, true, T2PV, vitB, nullptr, S4, LL, NVV, DD, 4 * DD, DD, 200,
            BB * HH, HH, (long long)LL * 4 * DD, DD, (long long)NVV * DD, 0,
            (long long)HH * LL * 200, (long long)LL * 200, inv_sqrt_d, nullptr);
  // 4. P = softmax(S) in place
  softmax_bf16<<<(BB * HH * LL + 3) / 4, 256, 0, stream>>>(S4, BB * HH * LL);
  // 5. Pv[b,:,h,:] = P[b,h] @ vit_b   (overwrites T2all slices)
  gemm<u16>(stream, false, S4, vitB, nullptr, T2PV, LL, DD, NVV, 200, DD, 4 * DD,
            BB * HH, HH, (long long)HH * LL * 200, (long long)LL * 200,
            (long long)NVV * DD, 0, (long long)LL * 4 * DD, DD, 1.f, nullptr);
  // 6. tii_pre = PvAll @ WvfAll^T + TFB   (K=3072, f32 out) — 240 blocks
  gemm_ph<2, 0><<<240, 512, 0, stream>>>(T2PV, Wvf, R_ACC, nullptr,
                                         nullptr, nullptr, nullptr, nullptr,
                                         BB * LL, DD, 4 * DD, 4 * DD, 4 * DD, DD, 6,
                                         nullptr, nullptr, TFB, nullptr, nullptr, 0);

  // ---- phase C ----
  // 7. tii = LN(tii_pre) + fused row norms
  ln_kernel<<<BB * LL, 256, 0, stream>>>(R_ACC, R_ACC, nullptr, mha_ln_g, mha_ln_b, nrm);
  // 8. adj_ti = adj * cos-sim
  sim_kernel<<<dim3(3, 3, BB), 256, 0, stream>>>(R_ACC, nrm, adj, adjtiB);
  // 9. den, den_ti
  den_kernel<<<BB * LL, 256, 0, stream>>>(adj, adjtiB, den, den_ti);
  // 10. span pools
  pool_kernel<u16><<<dim3(BB, LL), 256, 0, stream>>>(TFB, tmpsB, word_length, tran);
  pool_kernel<float><<<dim3(BB, LL), 256, 0, stream>>>(R_ACC, tmpsTiB, word_length, tran);
  // 11. h1 = adj @ tmps (f32 A direct) -> H1; h2 = adj_ti @ tmps_ti -> TFB
  gemm<float>(stream, false, adj, tmpsB, nullptr, H1, LL, DD, LL, LL, DD, DD,
              BB, 1, (long long)LL * LL, 0, sA_L, 0, sA_L, 0, 1.f, nullptr);
  gemm<u16>(stream, false, adjtiB, tmpsTiB, nullptr, h2B, LL, DD, LL, LL, DD, DD,
            BB, 1, (long long)LL * LL, 0, sA_L, 0, sA_L, 0, 1.f, nullptr);
  // 12. g1 = relu((h1 @ w1b + b1b) / den) -> vitB; g2 = relu((h2 @ w2b + b2b)/den_ti) -> BIG+BLD
  //     fused as one DUAL dispatch (240 blocks, two pointer-sets)
  gemm_ph<4, 1><<<240, 512, 0, stream>>>(H1, w1bT, nullptr, g1B,
                                         h2B, w2bT, nullptr, g2B,
                                         BB * LL, DD, DD, DD, DD, DD, 3,
                                         b1b, b2b, nullptr, den, den_ti, 1);
  // 13. masked means -> local_in bf16
  gcn_kernel<<<dim3(BB, 3), 256, 0, stream>>>(g1B, target_mask, linB, 0);
  gcn_kernel<<<dim3(BB, 3), 256, 0, stream>>>(g2B, target_mask, linB, DD);
  // 14. global_bert = LN(pooler_out)
  ln_kernel<<<BB, 256, 0, stream>>>(pooler_out, global_bert, nullptr, ln_g, ln_b, nullptr);
  // 15. local_feat = local_in @ loc_w + loc_b
  gemm<u16>(stream, true, linB, locT, local_feat, nullptr, BB, DD, 2 * DD, 2 * DD, 2 * DD, DD,
            1, 1, 0, 0, 0, 0, 0, 0, 1.f, loc_b);
  // 16. out
  final_kernel<<<BB * 3, 256, 0, stream>>>(global_bert, local_feat, out_w, out_b, out);
}

// Round 12
// 718.339 us; speedup vs baseline: 2.0854x; 1.0260x over previous
//
#include <hip/hip_runtime.h>
#include <math.h>

#define BB 64
#define LL 160
#define DD 768
#define HH 4
#define NVV 197
#define SS 159

typedef unsigned short u16;
typedef __attribute__((ext_vector_type(8))) short bf16x8;
typedef __attribute__((ext_vector_type(4))) float f32x4;

union QU { uint4 u; bf16x8 v; };

__device__ __forceinline__ u16 f2bf(float a) {
  unsigned u = __builtin_bit_cast(unsigned, a);
  u = (u + 0x7FFFu + ((u >> 16) & 1u)) >> 16;
  return (u16)u;
}
__device__ __forceinline__ unsigned f2bf2(float a, float b) {
  return (unsigned)f2bf(a) | ((unsigned)f2bf(b) << 16);
}
__device__ __forceinline__ float bf2f(u16 h) {
  unsigned u = ((unsigned)h) << 16;
  return __builtin_bit_cast(float, u);
}
__device__ __forceinline__ float to_f(float x) { return x; }
__device__ __forceinline__ float to_f(u16 x) { return bf2f(x); }

__device__ __forceinline__ void async16(const u16* g, void* l) {
  __builtin_amdgcn_global_load_lds(
      (const __attribute__((address_space(1))) void*)g,
      (__attribute__((address_space(3))) void*)l, 16, 0, 0);
}

__device__ __forceinline__ uint4 load_bf8(const u16* __restrict__ P, long long rowbase,
                                          int valid, int kb, int K) {
  uint4 r;
  if (valid && (kb + 8 <= K) && (((rowbase + kb) & 7) == 0)) {
    r = *(const uint4*)(P + rowbase + kb);
  } else {
    u16 e[8];
    #pragma unroll
    for (int i = 0; i < 8; ++i) { int k = kb + i; e[i] = (valid && k < K) ? P[rowbase + k] : (u16)0; }
    r.x = e[0] | ((unsigned)e[1] << 16); r.y = e[2] | ((unsigned)e[3] << 16);
    r.z = e[4] | ((unsigned)e[5] << 16); r.w = e[6] | ((unsigned)e[7] << 16);
  }
  return r;
}

__device__ __forceinline__ uint4 load_row8(const float* __restrict__ P, long long rowbase,
                                           int valid_row, int kb, int K) {
  float f[8];
  if (valid_row && (kb + 8 <= K)) {
    const float4* p0 = (const float4*)(P + rowbase + kb);
    float4 x = p0[0], y = p0[1];
    f[0] = x.x; f[1] = x.y; f[2] = x.z; f[3] = x.w;
    f[4] = y.x; f[5] = y.y; f[6] = y.z; f[7] = y.w;
  } else {
    #pragma unroll
    for (int e = 0; e < 8; ++e) { int k = kb + e; f[e] = (valid_row && k < K) ? P[rowbase + k] : 0.f; }
  }
  uint4 r;
  r.x = f2bf2(f[0], f[1]); r.y = f2bf2(f[2], f[3]);
  r.z = f2bf2(f[4], f[5]); r.w = f2bf2(f[6], f[7]);
  return r;
}

__device__ __forceinline__ uint4 load_a(const u16* P, long long rb, int v, int kb, int K) {
  return load_bf8(P, rb, v, kb, K);
}
__device__ __forceinline__ uint4 load_a(const float* P, long long rb, int v, int kb, int K) {
  return load_row8(P, rb, v, kb, K);
}

// ---------------- phase GEMM v2: BM={256,128}, BN=128, BK=32, dbuf issue-early ----------------
// C = A @ B^T (+bias) (+resid set0) (/rowdiv) (relu). Exact shapes only (BM|M, 128|N, 32|K).
// LDS 48KB (BM=256, 3 blk/CU) or 32KB (BM=128, 5 blk/CU).
template<int BMH, int DUAL>
__global__ __launch_bounds__(512) void gemm_ph(
    const u16* __restrict__ A0, const u16* __restrict__ B0m,
    float* __restrict__ Cf0, u16* __restrict__ Cb0,
    const u16* __restrict__ A1, const u16* __restrict__ B1m,
    float* __restrict__ Cf1, u16* __restrict__ Cb1,
    int M, int N, int K, int lda, int ldb, int ldc, int nbx,
    const float* __restrict__ bias0, const float* __restrict__ bias1,
    const u16* __restrict__ resid0,
    const float* __restrict__ rowdiv0, const float* __restrict__ rowdiv1,
    int relu) {
  constexpr int BM = BMH ? 128 : 256;
  constexpr int MR = BMH ? 4 : 8;

  __shared__ uint4 Al[2][4][BM];   // [buf][kslot][row] : 8 bf16 at k = k0 + kslot*8
  __shared__ uint4 Bl[2][4][128];

  int id = blockIdx.x;
  int nset = gridDim.x >> DUAL;
  int setid = DUAL ? (id >= nset ? 1 : 0) : 0;
  if (setid) id -= nset;
  const u16* A = setid ? A1 : A0;
  const u16* Bm = setid ? B1m : B0m;
  float* Cf = setid ? Cf1 : Cf0;
  u16* Cb = setid ? Cb1 : Cb0;
  const float* bias = setid ? bias1 : bias0;
  const float* rowdiv = setid ? rowdiv1 : rowdiv0;
  const u16* residB = setid ? (const u16*)nullptr : resid0;

  // bijective XCD swizzle within set
  int qq = nset >> 3, rr = nset & 7;
  int xcd = id & 7, idx = id >> 3;
  int swz = (xcd < rr ? xcd * (qq + 1) : rr * (qq + 1) + (xcd - rr) * qq) + idx;
  int bx = swz % nbx, by = swz / nbx;
  int row0 = by * BM, col0 = bx * 128;

  int t = threadIdx.x, l = t & 63, w = t >> 6;
  int wm = w >> 2, wn = w & 3;
  int li = l & 15, kg = l >> 4;
  int nt = K >> 5;
  int wks = w & 3;           // kslot this wave stages
  int wrg = (w >> 2) * 64;   // row-group base

  f32x4 acc[MR][2] = {};

  auto STAGE = [&](int kt, int bi) {
    long long ko = ((long long)kt << 5) + wks * 8;
    async16(Bm + (long long)(col0 + wrg + l) * ldb + ko, &Bl[bi][wks][wrg]);
    async16(A + (long long)(row0 + wrg + l) * lda + ko, &Al[bi][wks][wrg]);
    if (BM == 256)
      async16(A + (long long)(row0 + 128 + wrg + l) * lda + ko, &Al[bi][wks][128 + wrg]);
  };

  STAGE(0, 0);
  __syncthreads();
  int buf = 0;
  for (int kt = 0; kt < nt; ++kt) {
    if (kt + 1 < nt) STAGE(kt + 1, buf ^ 1);  // issue next tile first
    QU bF[2], aF[MR];
    bF[0].u = Bl[buf][kg][wn * 32 + li];
    bF[1].u = Bl[buf][kg][wn * 32 + 16 + li];
    #pragma unroll
    for (int m = 0; m < MR; ++m)
      aF[m].u = Al[buf][kg][wm * (MR * 16) + m * 16 + li];
    __builtin_amdgcn_s_setprio(1);
    #pragma unroll
    for (int m = 0; m < MR; ++m) {
      acc[m][0] = __builtin_amdgcn_mfma_f32_16x16x32_bf16(aF[m].v, bF[0].v, acc[m][0], 0, 0, 0);
      acc[m][1] = __builtin_amdgcn_mfma_f32_16x16x32_bf16(aF[m].v, bF[1].v, acc[m][1], 0, 0, 0);
    }
    __builtin_amdgcn_s_setprio(0);
    __syncthreads();  // next tile landed + all reads of buf done
    buf ^= 1;
  }

  #pragma unroll
  for (int m = 0; m < MR; ++m)
    #pragma unroll
    for (int n = 0; n < 2; ++n) {
      int col = col0 + wn * 32 + n * 16 + li;
      float bv = bias ? bias[col] : 0.f;
      #pragma unroll
      for (int r = 0; r < 4; ++r) {
        int row = row0 + wm * (MR * 16) + m * 16 + kg * 4 + r;
        long long ci = (long long)row * ldc + col;
        float v = acc[m][n][r] + bv;
        if (residB) v += bf2f(residB[ci]);
        if (rowdiv) v /= rowdiv[row];
        if (relu) v = fmaxf(v, 0.f);
        if (Cf) Cf[ci] = v;
        if (Cb) Cb[ci] = f2bf(v);
      }
    }
}

// ---------------- MFMA GEMM, 64x64 tile, two-level batched, A dtype templated ----------------
template<bool TRANSB, typename TA>
__global__ __launch_bounds__(256) void gemm_bf16(
    const TA* __restrict__ A, const u16* __restrict__ Bm,
    float* __restrict__ Cf, u16* __restrict__ Cb,
    int M, int N, int K, int lda, int ldb, int ldc, int Hb,
    long long sAb, long long sAh, long long sBb, long long sBh,
    long long sCb, long long sCh,
    float alpha, const float* __restrict__ bias) {
  int bb = blockIdx.z / Hb, hh = blockIdx.z % Hb;
  A += bb * sAb + hh * sAh;
  Bm += bb * sBb + hh * sBh;
  long long coff = bb * sCb + hh * sCh;

  __shared__ uint4 As4[4][64];
  __shared__ uint4 Bs4[4][64];

  int row0 = blockIdx.y * 64, col0 = blockIdx.x * 64;
  int t = threadIdx.x;
  int l = t & 63, w = t >> 6;
  int mq = (w >> 1) * 32, nq = (w & 1) * 32;

  int am = t >> 2, akq = t & 3;
  int bn = t & 63, bkq = t >> 6;

  f32x4 acc[2][2] = {};

  for (int k0 = 0; k0 < K; k0 += 32) {
    As4[akq][am] = load_a(A, (long long)(row0 + am) * lda, (row0 + am) < M, k0 + akq * 8, K);
    if (TRANSB) {
      Bs4[akq][am] = load_bf8(Bm, (long long)(col0 + am) * ldb, (col0 + am) < N, k0 + akq * 8, K);
    } else {
      int gn = col0 + bn;
      u16 e[8];
      #pragma unroll
      for (int i = 0; i < 8; ++i) {
        int k = k0 + bkq * 8 + i;
        e[i] = (gn < N && k < K) ? Bm[(long long)k * ldb + gn] : (u16)0;
      }
      uint4 r;
      r.x = e[0] | ((unsigned)e[1] << 16); r.y = e[2] | ((unsigned)e[3] << 16);
      r.z = e[4] | ((unsigned)e[5] << 16); r.w = e[6] | ((unsigned)e[7] << 16);
      Bs4[bkq][bn] = r;
    }
    __syncthreads();
    int kg = l >> 4, li = l & 15;
    QU a0, a1, b0, b1;
    a0.u = As4[kg][mq + li];
    a1.u = As4[kg][mq + 16 + li];
    b0.u = Bs4[kg][nq + li];
    b1.u = Bs4[kg][nq + 16 + li];
    acc[0][0] = __builtin_amdgcn_mfma_f32_16x16x32_bf16(a0.v, b0.v, acc[0][0], 0, 0, 0);
    acc[0][1] = __builtin_amdgcn_mfma_f32_16x16x32_bf16(a0.v, b1.v, acc[0][1], 0, 0, 0);
    acc[1][0] = __builtin_amdgcn_mfma_f32_16x16x32_bf16(a1.v, b0.v, acc[1][0], 0, 0, 0);
    acc[1][1] = __builtin_amdgcn_mfma_f32_16x16x32_bf16(a1.v, b1.v, acc[1][1], 0, 0, 0);
    __syncthreads();
  }

  #pragma unroll
  for (int i = 0; i < 2; ++i) {
    #pragma unroll
    for (int j = 0; j < 2; ++j) {
      int colj = col0 + nq + j * 16 + (l & 15);
      float bv = (bias && colj < N) ? bias[colj] : 0.f;
      #pragma unroll
      for (int r = 0; r < 4; ++r) {
        int gr = row0 + mq + i * 16 + (l >> 4) * 4 + r;
        if (gr < M && colj < N) {
          long long ci = coff + (long long)gr * ldc + colj;
          float v = acc[i][j][r] * alpha + bv;
          if (Cf) Cf[ci] = v;
          if (Cb) Cb[ci] = f2bf(v);
        }
      }
    }
  }
}

// ---------------- sim GEMM (bf16 tii) fused with cosine*adj epilogue -> adj_ti bf16 ----------------
__global__ __launch_bounds__(256) void sim_kernel(
    const u16* __restrict__ TII, const float* __restrict__ nrm,
    const float* __restrict__ adjf, u16* __restrict__ adjtiB) {
  int bb = blockIdx.z;
  const u16* T = TII + (long long)bb * LL * DD;

  __shared__ uint4 As4[4][64];
  __shared__ uint4 Bs4[4][64];

  int row0 = blockIdx.y * 64, col0 = blockIdx.x * 64;
  int t = threadIdx.x;
  int l = t & 63, w = t >> 6;
  int mq = (w >> 1) * 32, nq = (w & 1) * 32;
  int am = t >> 2, akq = t & 3;

  f32x4 acc[2][2] = {};

  for (int k0 = 0; k0 < DD; k0 += 32) {
    As4[akq][am] = load_bf8(T, (long long)(row0 + am) * DD, (row0 + am) < LL, k0 + akq * 8, DD);
    Bs4[akq][am] = load_bf8(T, (long long)(col0 + am) * DD, (col0 + am) < LL, k0 + akq * 8, DD);
    __syncthreads();
    int kg = l >> 4, li = l & 15;
    QU a0, a1, b0, b1;
    a0.u = As4[kg][mq + li];
    a1.u = As4[kg][mq + 16 + li];
    b0.u = Bs4[kg][nq + li];
    b1.u = Bs4[kg][nq + 16 + li];
    acc[0][0] = __builtin_amdgcn_mfma_f32_16x16x32_bf16(a0.v, b0.v, acc[0][0], 0, 0, 0);
    acc[0][1] = __builtin_amdgcn_mfma_f32_16x16x32_bf16(a0.v, b1.v, acc[0][1], 0, 0, 0);
    acc[1][0] = __builtin_amdgcn_mfma_f32_16x16x32_bf16(a1.v, b0.v, acc[1][0], 0, 0, 0);
    acc[1][1] = __builtin_amdgcn_mfma_f32_16x16x32_bf16(a1.v, b1.v, acc[1][1], 0, 0, 0);
    __syncthreads();
  }

  #pragma unroll
  for (int i = 0; i < 2; ++i) {
    #pragma unroll
    for (int j = 0; j < 2; ++j) {
      int colj = col0 + nq + j * 16 + (l & 15);
      #pragma unroll
      for (int r = 0; r < 4; ++r) {
        int gr = row0 + mq + i * 16 + (l >> 4) * 4 + r;
        if (gr < LL && colj < LL) {
          float nl = nrm[bb * LL + gr], nm = nrm[bb * LL + colj];
          long long ai = ((long long)bb * LL + gr) * LL + colj;
          float s = acc[i][j][r] / fmaxf(nl * nm, 1e-16f);
          adjtiB[ai] = f2bf(adjf[ai] * s);
        }
      }
    }
  }
}

// ---------------- block reduce ----------------
__device__ __forceinline__ float block_sum(float v, float* sm) {
  #pragma unroll
  for (int o = 32; o > 0; o >>= 1) v += __shfl_down(v, o);
  int lane = threadIdx.x & 63, w = threadIdx.x >> 6;
  if (lane == 0) sm[w] = v;
  __syncthreads();
  if (threadIdx.x == 0) sm[0] = sm[0] + sm[1] + sm[2] + sm[3];
  __syncthreads();
  float r = sm[0];
  __syncthreads();
  return r;
}

// ---------------- LayerNorm ----------------
__global__ __launch_bounds__(256) void ln_kernel(const float* __restrict__ x, float* __restrict__ yf,
                                                 u16* __restrict__ yb,
                                                 const float* __restrict__ g, const float* __restrict__ b,
                                                 float* __restrict__ nrmout) {
  __shared__ float sm[4];
  long long row = blockIdx.x;
  const float* xr = x + row * DD;
  int t = threadIdx.x;
  float v0 = xr[t], v1 = xr[t + 256], v2 = xr[t + 512];
  float s = block_sum(v0 + v1 + v2, sm);
  float m = s * (1.f / 768.f);
  float d0 = v0 - m, d1 = v1 - m, d2 = v2 - m;
  float vv = block_sum(d0 * d0 + d1 * d1 + d2 * d2, sm);
  float rstd = rsqrtf(vv * (1.f / 768.f) + 1e-5f);
  float y0 = d0 * rstd * g[t] + b[t];
  float y1 = d1 * rstd * g[t + 256] + b[t + 256];
  float y2 = d2 * rstd * g[t + 512] + b[t + 512];
  if (yf) { float* yr = yf + row * DD; yr[t] = y0; yr[t + 256] = y1; yr[t + 512] = y2; }
  if (yb) { u16* yr = yb + row * DD; yr[t] = f2bf(y0); yr[t + 256] = f2bf(y1); yr[t + 512] = f2bf(y2); }
  if (nrmout) {
    float s2 = block_sum(y0 * y0 + y1 * y1 + y2 * y2, sm);
    if (t == 0) nrmout[row] = sqrtf(s2);
  }
}

// ---------------- in-place bf16 softmax over rows of ld 200 ----------------
__global__ __launch_bounds__(256) void softmax_bf16(u16* __restrict__ SP, int nrows) {
  int row = blockIdx.x * 4 + (threadIdx.x >> 6);
  int lane = threadIdx.x & 63;
  if (row >= nrows) return;
  u16* ar = SP + (long long)row * 200;
  float vals[4];
  float mx = -1e30f;
  int cnt = 0;
  for (int i = lane; i < NVV; i += 64) { float v = bf2f(ar[i]); vals[cnt++] = v; mx = fmaxf(mx, v); }
  #pragma unroll
  for (int o = 32; o > 0; o >>= 1) mx = fmaxf(mx, __shfl_xor(mx, o));
  float sum = 0.f;
  for (int j = 0; j < cnt; ++j) { vals[j] = __expf(vals[j] - mx); sum += vals[j]; }
  #pragma unroll
  for (int o = 32; o > 0; o >>= 1) sum += __shfl_xor(sum, o);
  float inv = 1.f / sum;
  cnt = 0;
  for (int i = lane; i < NVV; i += 64) ar[i] = f2bf(vals[cnt++] * inv);
  for (int i = NVV + lane; i < 200; i += 64) ar[i] = 0;
}

// ---------------- direct span-sum pool ----------------
template<typename T>
__global__ __launch_bounds__(256) void pool_kernel(const T* __restrict__ src, u16* __restrict__ dst,
                                                   const int* __restrict__ wl, const int* __restrict__ tran) {
  int b = blockIdx.x, i = blockIdx.y, d = threadIdx.x;
  long long ob = ((long long)b * LL + i) * DD;
  float r0 = 0.f, r1 = 0.f, r2 = 0.f;
  if (i > 0 && (i - 1) < wl[b]) {
    int w = i - 1;
    int st = tran[(b * SS + w) * 2];
    int en = tran[(b * SS + w) * 2 + 1];
    const T* sb = src + (long long)b * LL * DD;
    for (int s = st; s < en; ++s) {
      const T* rp = sb + (long long)(1 + s) * DD;
      r0 += to_f(rp[d]); r1 += to_f(rp[d + 256]); r2 += to_f(rp[d + 512]);
    }
  }
  dst[ob + d] = f2bf(r0);
  dst[ob + d + 256] = f2bf(r1);
  dst[ob + d + 512] = f2bf(r2);
}

// ---------------- den / den_ti ----------------
__global__ __launch_bounds__(256) void den_kernel(const float* __restrict__ adjf, const u16* __restrict__ atB,
                                                  float* __restrict__ den, float* __restrict__ den_ti) {
  __shared__ float sm[4];
  int bl = blockIdx.x, m = threadIdx.x;
  float a = 0.f, at = 0.f;
  if (m < LL) {
    long long idx = (long long)bl * LL + m;
    a = adjf[idx];
    at = bf2f(atB[idx]);
  }
  float sa = block_sum(a, sm);
  float sat = block_sum(at, sm);
  if (m == 0) { den[bl] = sa + 1.f; den_ti[bl] = sat + 1.f; }
}

// ---------------- masked mean ----------------
__global__ __launch_bounds__(256) void gcn_kernel(const u16* __restrict__ g, const float* __restrict__ mask,
                                                  u16* __restrict__ outB, int coloff) {
  int b = blockIdx.x;
  int d = blockIdx.y * 256 + threadIdx.x;
  float s = 0.f, wn = 0.f;
  for (int l = 0; l < LL; ++l) {
    float mk = mask[b * LL + l];
    wn += mk;
    s += mk * bf2f(g[((long long)b * LL + l) * DD + d]);
  }
  outB[(long long)b * (2 * DD) + coloff + d] = f2bf(s / wn);
}

// ---------------- final ----------------
__global__ __launch_bounds__(256) void final_kernel(const float* __restrict__ gb, const float* __restrict__ lf,
                                                    const float* __restrict__ ow, const float* __restrict__ ob,
                                                    float* __restrict__ out) {
  __shared__ float sm[4];
  int b = blockIdx.x / 3, c = blockIdx.x % 3;
  int t = threadIdx.x;
  float s = 0.f;
  for (int k = t; k < DD; k += 256) {
    s += gb[b * DD + k] * ow[k * 3 + c];
    s += lf[b * DD + k] * ow[(DD + k) * 3 + c];
  }
  float tot = block_sum(s, sm);
  if (t == 0) out[b * 3 + c] = tot + ob[c];
}

// ---------------- f32 -> bf16 elementwise ----------------
__global__ __launch_bounds__(256) void conv_kernel(const float4* __restrict__ x, uint2* __restrict__ y, int n4) {
  int i = blockIdx.x * 256 + threadIdx.x;
  if (i < n4) {
    float4 v = x[i];
    uint2 o;
    o.x = f2bf2(v.x, v.y);
    o.y = f2bf2(v.z, v.w);
    y[i] = o;
  }
}

// ---------------- transpose-convert (f32 -> bf16) ----------------
__global__ __launch_bounds__(256) void tconv_kernel(const float* __restrict__ src, u16* __restrict__ dst,
                                                    int R, int C, int lds, int ldd) {
  __shared__ float sm[32][33];
  int t = threadIdx.x;
  int tx = t & 31, ty8 = t >> 5;
  int r0 = blockIdx.y * 32, c0 = blockIdx.x * 32;
  for (int i = ty8; i < 32; i += 8) {
    int r = r0 + i, c = c0 + tx;
    sm[i][tx] = (r < R && c < C) ? src[(long long)r * lds + c] : 0.f;
  }
  __syncthreads();
  for (int i = ty8; i < 32; i += 8) {
    int c = c0 + i, r = r0 + tx;
    if (c < C && r < R) dst[(long long)c * ldd + r] = f2bf(sm[tx][i]);
  }
}

// ---------------- batched vit transpose: (B,197,768) bf16 -> (B,768,208) bf16, zero-padded ----------------
__global__ __launch_bounds__(256) void vtrans_kernel(const u16* __restrict__ src, u16* __restrict__ dst) {
  __shared__ u16 sm[32][33];
  int b = blockIdx.z;
  int c0 = blockIdx.x * 32;  // j in [0,768)
  int r0 = blockIdx.y * 32;  // k in [0,208)
  int t = threadIdx.x, tx = t & 31, ty8 = t >> 5;
  const u16* sb = src + (long long)b * NVV * DD;
  for (int i = ty8; i < 32; i += 8) {
    int r = r0 + i, c = c0 + tx;
    sm[i][tx] = (r < NVV && c < DD) ? sb[(long long)r * DD + c] : (u16)0;
  }
  __syncthreads();
  u16* db = dst + (long long)b * DD * 208;
  for (int i = ty8; i < 32; i += 8) {
    int j = c0 + i, k = r0 + tx;
    if (j < DD && k < 208) db[(long long)j * 208 + k] = sm[tx][i];
  }
}

// ---------------- host wrappers ----------------
template<typename TA>
static void gemm(hipStream_t s, bool transb, const TA* A, const u16* B, float* Cf, u16* Cb,
                 int M, int N, int K, int lda, int ldb, int ldc, int batches, int Hb,
                 long long sAb, long long sAh, long long sBb, long long sBh,
                 long long sCb, long long sCh, float alpha, const float* bias) {
  dim3 g((N + 63) / 64, (M + 63) / 64, batches);
  if (transb)
    gemm_bf16<true, TA><<<g, 256, 0, s>>>(A, B, Cf, Cb, M, N, K, lda, ldb, ldc, Hb,
                                          sAb, sAh, sBb, sBh, sCb, sCh, alpha, bias);
  else
    gemm_bf16<false, TA><<<g, 256, 0, s>>>(A, B, Cf, Cb, M, N, K, lda, ldb, ldc, Hb,
                                           sAb, sAh, sBb, sBh, sCb, sCh, alpha, bias);
}

extern "C" void kernel_launch(void* const* d_in, const int* in_sizes, int n_in,
                              void* d_out, int out_size, void* d_ws, size_t ws_size,
                              hipStream_t stream) {
  const float* text_hidden = (const float*)d_in[0];
  const float* vit_feature = (const float*)d_in[1];
  const float* pooler_out = (const float*)d_in[2];
  const float* target_mask = (const float*)d_in[3];
  const float* adj = (const float*)d_in[4];
  const float* ln_g = (const float*)d_in[5];
  const float* ln_b = (const float*)d_in[6];
  const float* wq = (const float*)d_in[7];
  const float* wk = (const float*)d_in[8];
  const float* wv = (const float*)d_in[9];
  const float* fc_w = (const float*)d_in[10];
  const float* mha_ln_g = (const float*)d_in[11];
  const float* mha_ln_b = (const float*)d_in[12];
  const float* w1b = (const float*)d_in[15];
  const float* b1b = (const float*)d_in[16];
  const float* w2b = (const float*)d_in[19];
  const float* b2b = (const float*)d_in[20];
  const float* loc_w = (const float*)d_in[21];
  const float* loc_b = (const float*)d_in[22];
  const float* out_w = (const float*)d_in[23];
  const float* out_b = (const float*)d_in[24];
  const int* word_length = (const int*)d_in[25];
  const int* tran = (const int*)d_in[26];
  float* out = (float*)d_out;

  const long long BLD = (long long)BB * LL * DD;   // 7,864,320
  const long long BND = (long long)BB * NVV * DD;  // 9,682,944
  const long long WHD = (long long)768 * 768;      // 589,824
  const long long W3K = (long long)768 * 3072;     // 2,359,296

  char* base = (char*)d_ws;
  auto alloc = [&](size_t bytes) { char* p = base; base += (bytes + 255) & ~(size_t)255; return p; };

  float* R_ACC = (float*)alloc(BLD * 4);                 // tii_pre (f32); early: vitT alias
  u16* TFB = (u16*)alloc(BLD * 2);                       // text_feat -> h2
  u16* vitB = (u16*)alloc(BND * 2);                      // vit bf16 -> tmps -> g1
  u16* BIG = (u16*)alloc((size_t)4 * BLD * 2);           // wq/wk/wv/fcT | T2all->PvAll | TIIB,tmpsTi,g2
  u16* Mt = (u16*)alloc((size_t)4 * WHD * 2);            // MtAll (3072 x 768)
  u16* Wvf = (u16*)alloc((size_t)4 * WHD * 2);           // WvfAll (768 x 3072)
  u16* SH = (u16*)alloc((size_t)BB * HH * LL * 200 * 2); // S4/P4 (ld 200) -> h1
  u16* adjtiB = (u16*)alloc((size_t)BB * LL * LL * 2);
  u16* w1bT = (u16*)alloc(WHD * 2);
  u16* w2bT = (u16*)alloc(WHD * 2);
  u16* locT = (u16*)alloc((size_t)768 * 1536 * 2);
  u16* linB = (u16*)alloc((size_t)BB * 1536 * 2);
  float* nrm = (float*)alloc((size_t)BB * LL * 4);
  float* den = (float*)alloc((size_t)BB * LL * 4);
  float* den_ti = (float*)alloc((size_t)BB * LL * 4);
  float* global_bert = (float*)alloc((size_t)BB * DD * 4);
  float* local_feat = (float*)alloc((size_t)BB * DD * 4);

  // region aliases
  u16* wqB = BIG;
  u16* wkB = BIG + W3K;
  u16* wvB = BIG + 2 * W3K;
  u16* fcT = BIG + 3 * W3K;
  u16* T2PV = BIG;                 // (10240 x 3072), dead after step 6
  u16* TIIB = BIG + 2 * BLD;       // bf16 tii, written step 7
  u16* tmpsTiB = BIG;              // step 10+
  u16* g2B = BIG + BLD;
  u16* S4 = SH;
  u16* H1 = SH;
  u16* tmpsB = vitB;
  u16* h2B = TFB;
  u16* g1B = vitB;
  u16* vitT = (u16*)R_ACC;         // (B,768,208) bf16; dead before R_ACC written (step 6)

  const float inv_sqrt_d = 1.0f / sqrtf((float)DD);
  const long long sA_L = (long long)LL * DD;

  // ---- phase A: conversions + folded-weight precompute ----
  {
    int n4v = (int)(BND / 4);
    conv_kernel<<<(n4v + 255) / 256, 256, 0, stream>>>((const float4*)vit_feature, (uint2*)vitB, n4v);
    vtrans_kernel<<<dim3(24, 7, BB), 256, 0, stream>>>(vitB, vitT);
    int n4w = (int)(W3K / 4);
    conv_kernel<<<(n4w + 255) / 256, 256, 0, stream>>>((const float4*)wq, (uint2*)wqB, n4w);
    conv_kernel<<<(n4w + 255) / 256, 256, 0, stream>>>((const float4*)wk, (uint2*)wkB, n4w);
    conv_kernel<<<(n4w + 255) / 256, 256, 0, stream>>>((const float4*)wv, (uint2*)wvB, n4w);
    for (int h = 0; h < HH; ++h)
      tconv_kernel<<<dim3(24, 24), 256, 0, stream>>>(fc_w + (size_t)h * WHD, fcT + (size_t)h * WHD,
                                                     768, 768, 768, 768);
    tconv_kernel<<<dim3(24, 24), 256, 0, stream>>>(w1b, w1bT, 768, 768, 768, 768);
    tconv_kernel<<<dim3(24, 24), 256, 0, stream>>>(w2b, w2bT, 768, 768, 768, 768);
    tconv_kernel<<<dim3(24, 48), 256, 0, stream>>>(loc_w, locT, 1536, 768, 768, 1536);
    gemm<u16>(stream, true, wkB, wqB, nullptr, Mt, 768, 768, 768, 3072, 3072, 768,
              HH, 1, 768, 0, 768, 0, WHD, 0, 1.f, nullptr);
    gemm<u16>(stream, true, fcT, wvB, nullptr, Wvf, 768, 768, 768, 768, 3072, 3072,
              HH, 1, WHD, 0, 768, 0, 768, 0, 1.f, nullptr);
  }

  // ---- phase B: attention (head-merged, folded weights) ----
  // 1. text_feat = LN(text_hidden) -> bf16
  ln_kernel<<<BB * LL, 256, 0, stream>>>(text_hidden, nullptr, TFB, ln_g, ln_b, nullptr);
  // 2. T2all = TFB @ MtAll^T   (10240 x 3072) — BM=256 phase kernel, 960 blocks
  gemm_ph<0, 0><<<960, 512, 0, stream>>>(TFB, Mt, nullptr, T2PV,
                                         nullptr, nullptr, nullptr, nullptr,
                                         BB * LL, 4 * DD, DD, DD, DD, 4 * DD, 24,
                                         nullptr, nullptr, nullptr, nullptr, nullptr, 0);
  // 3. S[b,h] = T2[b,:,h,:] @ vit_b^T / sqrt(D) -> bf16 logits (ld 200)
  gemm<u16>(stream, true, T2PV, vitB, nullptr, S4, LL, NVV, DD, 4 * DD, DD, 200,
            BB * HH, HH, (long long)LL * 4 * DD, DD, (long long)NVV * DD, 0,
            (long long)HH * LL * 200, (long long)LL * 200, inv_sqrt_d, nullptr);
  // 4. P = softmax(S) in place
  softmax_bf16<<<(BB * HH * LL + 3) / 4, 256, 0, stream>>>(S4, BB * HH * LL);
  // 5. Pv[b,:,h,:] = P[b,h] @ vit_b = P @ vitT^T   (vector TRANSB path)
  gemm<u16>(stream, true, S4, vitT, nullptr, T2PV, LL, DD, NVV, 200, 208, 4 * DD,
            BB * HH, HH, (long long)HH * LL * 200, (long long)LL * 200,
            (long long)DD * 208, 0, (long long)LL * 4 * DD, DD, 1.f, nullptr);
  // 6. tii_pre = PvAll @ WvfAll^T + TFB   (K=3072, f32 out) — BM=128, 480 blocks
  gemm_ph<1, 0><<<480, 512, 0, stream>>>(T2PV, Wvf, R_ACC, nullptr,
                                         nullptr, nullptr, nullptr, nullptr,
                                         BB * LL, DD, 4 * DD, 4 * DD, 4 * DD, DD, 6,
                                         nullptr, nullptr, TFB, nullptr, nullptr, 0);

  // ---- phase C ----
  // 7. tii = LN(tii_pre) -> bf16 TIIB + row norms
  ln_kernel<<<BB * LL, 256, 0, stream>>>(R_ACC, nullptr, TIIB, mha_ln_g, mha_ln_b, nrm);
  // 8. adj_ti = adj * cos-sim (bf16 tii)
  sim_kernel<<<dim3(3, 3, BB), 256, 0, stream>>>(TIIB, nrm, adj, adjtiB);
  // 9. den, den_ti
  den_kernel<<<BB * LL, 256, 0, stream>>>(adj, adjtiB, den, den_ti);
  // 10. span pools (both bf16 sources)
  pool_kernel<u16><<<dim3(BB, LL), 256, 0, stream>>>(TFB, tmpsB, word_length, tran);
  pool_kernel<u16><<<dim3(BB, LL), 256, 0, stream>>>(TIIB, tmpsTiB, word_length, tran);
  // 11. h1 = adj @ tmps (f32 A) -> H1; h2 = adj_ti @ tmps_ti -> TFB
  gemm<float>(stream, false, adj, tmpsB, nullptr, H1, LL, DD, LL, LL, DD, DD,
              BB, 1, (long long)LL * LL, 0, sA_L, 0, sA_L, 0, 1.f, nullptr);
  gemm<u16>(stream, false, adjtiB, tmpsTiB, nullptr, h2B, LL, DD, LL, LL, DD, DD,
            BB, 1, (long long)LL * LL, 0, sA_L, 0, sA_L, 0, 1.f, nullptr);
  // 12. g1/g2 fused DUAL (BM=128): 960 blocks
  gemm_ph<1, 1><<<960, 512, 0, stream>>>(H1, w1bT, nullptr, g1B,
                                         h2B, w2bT, nullptr, g2B,
                                         BB * LL, DD, DD, DD, DD, DD, 6,
                                         b1b, b2b, nullptr, den, den_ti, 1);
  // 13. masked means -> local_in bf16
  gcn_kernel<<<dim3(BB, 3), 256, 0, stream>>>(g1B, target_mask, linB, 0);
  gcn_kernel<<<dim3(BB, 3), 256, 0, stream>>>(g2B, target_mask, linB, DD);
  // 14. global_bert = LN(pooler_out)
  ln_kernel<<<BB, 256, 0, stream>>>(pooler_out, global_bert, nullptr, ln_g, ln_b, nullptr);
  // 15. local_feat = local_in @ loc_w + loc_b
  gemm<u16>(stream, true, linB, locT, local_feat, nullptr, BB, DD, 2 * DD, 2 * DD, 2 * DD, DD,
            1, 1, 0, 0, 0, 0, 0, 0, 1.f, loc_b);
  // 16. out
  final_kernel<<<BB * 3, 256, 0, stream>>>(global_bert, local_feat, out_w, out_b, out);
}